// Round 5
// baseline (299.345 us; speedup 1.0000x reference)
//
#include <hip/hip_runtime.h>
#include <hip/hip_bf16.h>
#include <math.h>

typedef _Float16 f16;
typedef _Float16 half8 __attribute__((ext_vector_type(8)));
typedef float f32x4 __attribute__((ext_vector_type(4)));
typedef float f32x16 __attribute__((ext_vector_type(16)));
typedef unsigned int u32;

#define NB 8
#define NS 1024
#define DM 1024
#define NH 16
#define NF 64

// ---------------------------------------------------------------------------
// convert sin f32 -> f16 (8 elems/thread)
// ---------------------------------------------------------------------------
__global__ __launch_bounds__(256) void csin_kernel(const float* __restrict__ in, f16* __restrict__ out) {
  long gid = (long)blockIdx.x * 256 + threadIdx.x;
  const float4* p = (const float4*)(in + gid * 8);
  float4 a = p[0], b = p[1];
  half8 v;
  v[0] = (f16)a.x; v[1] = (f16)a.y; v[2] = (f16)a.z; v[3] = (f16)a.w;
  v[4] = (f16)b.x; v[5] = (f16)b.y; v[6] = (f16)b.z; v[7] = (f16)b.w;
  *(half8*)(out + gid * 8) = v;
}

// W2T[n][d] = Wx[n>>6][d][n&63]
__global__ __launch_bounds__(256) void cwx_kernel(const float* __restrict__ Wx, f16* __restrict__ W2T) {
  int gid = blockIdx.x * 256 + threadIdx.x;
  int n = gid >> 7;
  int d0 = (gid & 127) * 8;
  const float* src = Wx + (n >> 6) * (DM * NF) + (n & 63);
  half8 v;
#pragma unroll
  for (int j = 0; j < 8; ++j) v[j] = (f16)src[(size_t)(d0 + j) * NF];
  *(half8*)(W2T + (size_t)n * DM + d0) = v;
}

// WpT[n][d] = Wp[d][n]
__global__ __launch_bounds__(256) void cwp_kernel(const float* __restrict__ Wp, f16* __restrict__ WpT) {
  int gid = blockIdx.x * 256 + threadIdx.x;
  int n = gid >> 7;
  int d0 = (gid & 127) * 8;
  const float* src = Wp + n;
  half8 v;
#pragma unroll
  for (int j = 0; j < 8; ++j) v[j] = (f16)src[(size_t)(d0 + j) * DM];
  *(half8*)(WpT + (size_t)n * DM + d0) = v;
}

// ---------------------------------------------------------------------------
// GEMM v2: C[8192,1024] = A @ Bt^T + bias. 128x128 tile, BK=64, m97 pattern:
// linear LDS + global_load_lds width 16.
// ---------------------------------------------------------------------------
template <int MODE>
__global__ __launch_bounds__(256) void gemm_kernel(const f16* __restrict__ A, const f16* __restrict__ Bt,
                                                   const float* __restrict__ bias, void* __restrict__ Cv) {
  __shared__ f16 As[128][64];
  __shared__ f16 Bs[128][64];
  int tid = threadIdx.x;
  int l = tid & 63, wv = tid >> 6;
  int wm = wv >> 1, wn = wv & 1;
  int bm = blockIdx.x >> 3, bn = blockIdx.x & 7;
  int lr = l & 15, lh = l >> 4;

  f32x4 acc[4][4];
#pragma unroll
  for (int i = 0; i < 4; ++i)
#pragma unroll
    for (int j = 0; j < 4; ++j) acc[i][j] = (f32x4)0.f;

  // staging: wave wv, call c covers rows [wv*32 + c*8, +8) x 64 cols (1 KB)
  const f16* gA = A + (size_t)(bm * 128 + wv * 32 + (l >> 3)) * DM + (l & 7) * 8;
  const f16* gB = Bt + (size_t)(bn * 128 + wv * 32 + (l >> 3)) * DM + (l & 7) * 8;
  f16* ldsA = &As[wv * 32][0];
  f16* ldsB = &Bs[wv * 32][0];

  for (int k0 = 0; k0 < DM; k0 += 64) {
    __syncthreads();
#pragma unroll
    for (int c = 0; c < 4; ++c) {
      __builtin_amdgcn_global_load_lds(
          (const __attribute__((address_space(1))) void*)(gA + k0 + (size_t)c * 8 * DM),
          (__attribute__((address_space(3))) void*)(ldsA + c * 512), 16, 0, 0);
      __builtin_amdgcn_global_load_lds(
          (const __attribute__((address_space(1))) void*)(gB + k0 + (size_t)c * 8 * DM),
          (__attribute__((address_space(3))) void*)(ldsB + c * 512), 16, 0, 0);
    }
    __syncthreads();
#pragma unroll
    for (int ks = 0; ks < 2; ++ks) {
      half8 af[4], bf[4];
#pragma unroll
      for (int mi = 0; mi < 4; ++mi) af[mi] = *(const half8*)&As[wm * 64 + mi * 16 + lr][ks * 32 + lh * 8];
#pragma unroll
      for (int ni = 0; ni < 4; ++ni) bf[ni] = *(const half8*)&Bs[wn * 64 + ni * 16 + lr][ks * 32 + lh * 8];
#pragma unroll
      for (int mi = 0; mi < 4; ++mi)
#pragma unroll
        for (int ni = 0; ni < 4; ++ni)
          acc[mi][ni] = __builtin_amdgcn_mfma_f32_16x16x32_f16(af[mi], bf[ni], acc[mi][ni], 0, 0, 0);
    }
  }

#pragma unroll
  for (int mi = 0; mi < 4; ++mi)
#pragma unroll
    for (int ni = 0; ni < 4; ++ni) {
      int gc = bn * 128 + wn * 64 + ni * 16 + lr;
      float bv = bias[gc];
#pragma unroll
      for (int r = 0; r < 4; ++r) {
        int gr = bm * 128 + wm * 64 + mi * 16 + lh * 4 + r;
        float v = acc[mi][ni][r] + bv;
        if (MODE == 0) {
          f16* x = (f16*)Cv;
          int b = gr >> 10, s = gr & 1023, h = gc >> 6, f = gc & 63;
          x[(size_t)((b * NH + h) * NS + s) * NF + f] = (f16)v;
        } else {
          ((float*)Cv)[(size_t)gr * DM + gc] = v;
        }
      }
    }
}

// ---------------------------------------------------------------------------
// transx: xT[bh][f][s] = x[bh][s][f]  (raw values, for PV V-fragments)
// 64x64 LDS tile, XOR-swizzled so the gather reads are conflict-free.
// ---------------------------------------------------------------------------
__global__ __launch_bounds__(256) void transx_kernel(const f16* __restrict__ x, f16* __restrict__ xT) {
  __shared__ f16 T[64][64];
  int bh = blockIdx.x >> 4, s0 = (blockIdx.x & 15) * 64;
  int tid = threadIdx.x;
  const f16* xb = x + (size_t)bh * (NS * NF);
#pragma unroll
  for (int it = 0; it < 2; ++it) {
    int idx = it * 256 + tid;
    int sr = idx >> 3, fcb = idx & 7;
    half8 v = *(const half8*)(xb + (size_t)(s0 + sr) * NF + fcb * 8);
    *(half8*)&T[sr][((fcb ^ ((sr >> 3) & 7)) * 8)] = v;
  }
  __syncthreads();
#pragma unroll
  for (int it = 0; it < 2; ++it) {
    int idx = it * 256 + tid;
    int fr = idx >> 3, scb = idx & 7;
    half8 v;
#pragma unroll
    for (int j = 0; j < 8; ++j) v[j] = T[scb * 8 + j][(((fr >> 3) ^ scb) * 8) + (fr & 7)];
    *(half8*)(xT + ((size_t)bh * NF + fr) * NS + s0 + scb * 8) = v;
  }
}

// ---------------------------------------------------------------------------
// normx: x <- x / ||x_row||  in place (rows of 64 f16; 4 lanes per row)
// ---------------------------------------------------------------------------
__global__ __launch_bounds__(256) void normx_kernel(f16* __restrict__ x) {
  int gid = blockIdx.x * 256 + threadIdx.x;
  int row = gid >> 2, sub = gid & 3;
  f16* p = x + (size_t)row * NF + sub * 16;
  half8 a = *(const half8*)p;
  half8 b = *(const half8*)(p + 8);
  float ss = 0.f;
#pragma unroll
  for (int i = 0; i < 8; ++i) {
    float u = (float)a[i], w = (float)b[i];
    ss += u * u + w * w;
  }
  ss += __shfl_xor(ss, 1, 64);
  ss += __shfl_xor(ss, 2, 64);
  float inv = rsqrtf(ss);
  half8 an, bn;
#pragma unroll
  for (int i = 0; i < 8; ++i) {
    an[i] = (f16)((float)a[i] * inv);
    bn[i] = (f16)((float)b[i] * inv);
  }
  *(half8*)p = an;
  *(half8*)(p + 8) = bn;
}

// ---------------------------------------------------------------------------
// attn v3: LDS-free, 32x32x16 MFMA, swapped QK^T (S^T = K.Q^T), in-register
// softmax (fixed max = 1 since cosine <= 1) + cvt_pkrtz/shfl P-redistribution.
// xn = normalized x (Q,K operands); xT = raw transposed x (V operand).
// Block = 4 independent waves, each owns 32 q columns.
// ---------------------------------------------------------------------------
__global__ __launch_bounds__(256) void attn_kernel(const f16* __restrict__ xn, const f16* __restrict__ xT,
                                                   f16* __restrict__ ao) {
  int tid = threadIdx.x;
  int l = tid & 63, wv = tid >> 6;
  int lq = l & 31, hi = l >> 5;
  int kq = hi * 8;
  int bh = blockIdx.x >> 3, q0 = (blockIdx.x & 7) * 128;
  const f16* xnb = xn + (size_t)bh * (NS * NF);
  const f16* xTb = xT + (size_t)bh * (NF * NS);

  int q = q0 + wv * 32 + lq;

  // Q fragments (B-operand of S^T): col = q, k = f
  half8 bq[4];
#pragma unroll
  for (int ks = 0; ks < 4; ++ks)
    bq[ks] = *(const half8*)(xnb + (size_t)q * NF + ks * 16 + kq);

  f32x16 accO[2];
  accO[0] = (f32x16)0.f;
  accO[1] = (f32x16)0.f;
  float rs = 0.f;

  for (int t0 = 0; t0 < NS; t0 += 128) {
#pragma unroll
    for (int ti = 0; ti < 4; ++ti) {
      // ---- S^T[t-tile 32][q-tile 32] ----
      f32x16 sa = (f32x16)0.f;
      int tr = t0 + ti * 32 + lq;
#pragma unroll
      for (int ks = 0; ks < 4; ++ks) {
        half8 ak = *(const half8*)(xnb + (size_t)tr * NF + ks * 16 + kq);
        sa = __builtin_amdgcn_mfma_f32_32x32x16_f16(ak, bq[ks], sa, 0, 0, 0);
      }
      // ---- exp(s-1) with ==0 quirk; pack to f16 pairs (consecutive t) ----
      u32 pk[8];
#pragma unroll
      for (int m = 0; m < 8; ++m) {
        float a = sa[2 * m], b = sa[2 * m + 1];
        float ea = (a == 0.f) ? 0.f : __expf(a - 1.f);
        float eb = (b == 0.f) ? 0.f : __expf(b - 1.f);
        rs += ea + eb;
        auto h = __builtin_amdgcn_cvt_pkrtz(ea, eb);
        pk[m] = __builtin_bit_cast(u32, h);
      }
      // ---- redistribute P into PV A-fragments (partner = lane ^ 32) ----
      u32 sw[8];
#pragma unroll
      for (int m = 0; m < 8; ++m) sw[m] = (u32)__shfl_xor((int)pk[m], 32, 64);
      bool lo = (hi == 0);
      uint4 a0, a1;
      a0.x = lo ? pk[0] : sw[2];
      a0.y = lo ? pk[1] : sw[3];
      a0.z = lo ? sw[0] : pk[2];
      a0.w = lo ? sw[1] : pk[3];
      a1.x = lo ? pk[4] : sw[6];
      a1.y = lo ? pk[5] : sw[7];
      a1.z = lo ? sw[4] : pk[6];
      a1.w = lo ? sw[5] : pk[7];
      half8 pa0 = __builtin_bit_cast(half8, a0);
      half8 pa1 = __builtin_bit_cast(half8, a1);
      // ---- PV: O[q][f] += P[q][t] * V[t][f] over this 32-t tile ----
#pragma unroll
      for (int sub = 0; sub < 2; ++sub) {
        half8 pa = sub ? pa1 : pa0;
#pragma unroll
        for (int ni = 0; ni < 2; ++ni) {
          half8 vb = *(const half8*)(xTb + (size_t)(ni * 32 + lq) * NS + t0 + ti * 32 + sub * 16 + kq);
          accO[ni] = __builtin_amdgcn_mfma_f32_32x32x16_f16(pa, vb, accO[ni], 0, 0, 0);
        }
      }
    }
  }

  // rowsum: lane and its partner (lane^32) hold complementary t-subsets of q=lq
  rs += __shfl_xor(rs, 32, 64);

  int b = bh >> 4, h = bh & 15;
#pragma unroll
  for (int r = 0; r < 16; ++r) {
    int qoff = (r & 3) + 8 * (r >> 2) + 4 * hi;
    float rv = __shfl(rs, qoff, 64);  // rs_total for q-row qoff lives at lane qoff
    float rinv = 1.0f / rv;
    int qg = q0 + wv * 32 + qoff;
#pragma unroll
    for (int ni = 0; ni < 2; ++ni) {
      int f = ni * 32 + lq;
      ao[((size_t)(b * NS + qg)) * DM + h * NF + f] = (f16)(accO[ni][r] * rinv);
    }
  }
}

extern "C" void kernel_launch(void* const* d_in, const int* in_sizes, int n_in,
                              void* d_out, int out_size, void* d_ws, size_t ws_size,
                              hipStream_t stream) {
  const float* sin_in = (const float*)d_in[0];
  // d_in[1] = mask (presence-only in reference)
  const float* Wx = (const float*)d_in[2];
  const float* bx = (const float*)d_in[3];
  const float* Wp = (const float*)d_in[4];
  const float* bp = (const float*)d_in[5];
  float* out = (float*)d_out;

  char* p = (char*)d_ws;
  f16* sinb = (f16*)p;                      p += (size_t)NB * NS * DM * 2;      // also reused as ao
  f16* x    = (f16*)p;                      p += (size_t)NB * NH * NS * NF * 2; // normalized in place
  f16* xT   = (f16*)p;                      p += (size_t)NB * NH * NF * NS * 2;
  f16* W2T  = (f16*)p;                      p += (size_t)DM * DM * 2;
  f16* WpT  = (f16*)p;                      p += (size_t)DM * DM * 2;
  f16* ao   = sinb;  // sinb dead after gemm<0>

  csin_kernel<<<4096, 256, 0, stream>>>(sin_in, sinb);
  cwx_kernel<<<512, 256, 0, stream>>>(Wx, W2T);
  cwp_kernel<<<512, 256, 0, stream>>>(Wp, WpT);
  gemm_kernel<0><<<512, 256, 0, stream>>>(sinb, W2T, bx, (void*)x);
  transx_kernel<<<2048, 256, 0, stream>>>(x, xT);   // raw V, transposed
  normx_kernel<<<2048, 256, 0, stream>>>(x);        // x -> x/||x|| in place
  attn_kernel<<<1024, 256, 0, stream>>>(x, xT, ao);
  gemm_kernel<1><<<512, 256, 0, stream>>>(ao, WpT, bp, (void*)out);
}

// Round 7
// 295.356 us; speedup vs baseline: 1.0135x; 1.0135x over previous
//
#include <hip/hip_runtime.h>
#include <hip/hip_bf16.h>
#include <math.h>

typedef _Float16 f16;
typedef _Float16 half8 __attribute__((ext_vector_type(8)));
typedef float f32x4 __attribute__((ext_vector_type(4)));
typedef float f32x16 __attribute__((ext_vector_type(16)));
typedef unsigned int u32;

#define NB 8
#define NS 1024
#define DM 1024
#define NH 16
#define NF 64

// ---------------------------------------------------------------------------
// convert sin f32 -> f16 (8 elems/thread)
// ---------------------------------------------------------------------------
__global__ __launch_bounds__(256) void csin_kernel(const float* __restrict__ in, f16* __restrict__ out) {
  long gid = (long)blockIdx.x * 256 + threadIdx.x;
  const float4* p = (const float4*)(in + gid * 8);
  float4 a = p[0], b = p[1];
  half8 v;
  v[0] = (f16)a.x; v[1] = (f16)a.y; v[2] = (f16)a.z; v[3] = (f16)a.w;
  v[4] = (f16)b.x; v[5] = (f16)b.y; v[6] = (f16)b.z; v[7] = (f16)b.w;
  *(half8*)(out + gid * 8) = v;
}

// W2T[n][d] = Wx[n>>6][d][n&63]
__global__ __launch_bounds__(256) void cwx_kernel(const float* __restrict__ Wx, f16* __restrict__ W2T) {
  int gid = blockIdx.x * 256 + threadIdx.x;
  int n = gid >> 7;
  int d0 = (gid & 127) * 8;
  const float* src = Wx + (n >> 6) * (DM * NF) + (n & 63);
  half8 v;
#pragma unroll
  for (int j = 0; j < 8; ++j) v[j] = (f16)src[(size_t)(d0 + j) * NF];
  *(half8*)(W2T + (size_t)n * DM + d0) = v;
}

// WpT[n][d] = Wp[d][n]
__global__ __launch_bounds__(256) void cwp_kernel(const float* __restrict__ Wp, f16* __restrict__ WpT) {
  int gid = blockIdx.x * 256 + threadIdx.x;
  int n = gid >> 7;
  int d0 = (gid & 127) * 8;
  const float* src = Wp + n;
  half8 v;
#pragma unroll
  for (int j = 0; j < 8; ++j) v[j] = (f16)src[(size_t)(d0 + j) * DM];
  *(half8*)(WpT + (size_t)n * DM + d0) = v;
}

// ---------------------------------------------------------------------------
// GEMM v2: C[8192,1024] = A @ Bt^T + bias. 128x128 tile, BK=64,
// linear LDS + global_load_lds width 16. XCD-grouped block swizzle: each XCD
// owns a contiguous bm-group (A-slab) x all bn -> per-XCD fetch ~4MB not 17MB.
// ---------------------------------------------------------------------------
template <int MODE>
__global__ __launch_bounds__(256) void gemm_kernel(const f16* __restrict__ A, const f16* __restrict__ Bt,
                                                   const float* __restrict__ bias, void* __restrict__ Cv) {
  __shared__ f16 As[128][64];
  __shared__ f16 Bs[128][64];
  int tid = threadIdx.x;
  int l = tid & 63, wv = tid >> 6;
  int wm = wv >> 1, wn = wv & 1;
  // XCD swizzle: xcd = bid&7 constant within a bm-group of 8 bn-blocks
  int xcd = blockIdx.x & 7, m = blockIdx.x >> 3;
  int bm = ((m >> 3) << 3) | xcd;  // bm % 8 == xcd
  int bn = m & 7;
  int lr = l & 15, lh = l >> 4;

  f32x4 acc[4][4];
#pragma unroll
  for (int i = 0; i < 4; ++i)
#pragma unroll
    for (int j = 0; j < 4; ++j) acc[i][j] = (f32x4)0.f;

  // staging: wave wv, call c covers rows [wv*32 + c*8, +8) x 64 cols (1 KB)
  const f16* gA = A + (size_t)(bm * 128 + wv * 32 + (l >> 3)) * DM + (l & 7) * 8;
  const f16* gB = Bt + (size_t)(bn * 128 + wv * 32 + (l >> 3)) * DM + (l & 7) * 8;
  f16* ldsA = &As[wv * 32][0];
  f16* ldsB = &Bs[wv * 32][0];

  for (int k0 = 0; k0 < DM; k0 += 64) {
    __syncthreads();
#pragma unroll
    for (int c = 0; c < 4; ++c) {
      __builtin_amdgcn_global_load_lds(
          (const __attribute__((address_space(1))) void*)(gA + k0 + (size_t)c * 8 * DM),
          (__attribute__((address_space(3))) void*)(ldsA + c * 512), 16, 0, 0);
      __builtin_amdgcn_global_load_lds(
          (const __attribute__((address_space(1))) void*)(gB + k0 + (size_t)c * 8 * DM),
          (__attribute__((address_space(3))) void*)(ldsB + c * 512), 16, 0, 0);
    }
    __syncthreads();
#pragma unroll
    for (int ks = 0; ks < 2; ++ks) {
      half8 af[4], bf[4];
#pragma unroll
      for (int mi = 0; mi < 4; ++mi) af[mi] = *(const half8*)&As[wm * 64 + mi * 16 + lr][ks * 32 + lh * 8];
#pragma unroll
      for (int ni = 0; ni < 4; ++ni) bf[ni] = *(const half8*)&Bs[wn * 64 + ni * 16 + lr][ks * 32 + lh * 8];
#pragma unroll
      for (int mi = 0; mi < 4; ++mi)
#pragma unroll
        for (int ni = 0; ni < 4; ++ni)
          acc[mi][ni] = __builtin_amdgcn_mfma_f32_16x16x32_f16(af[mi], bf[ni], acc[mi][ni], 0, 0, 0);
    }
  }

#pragma unroll
  for (int mi = 0; mi < 4; ++mi)
#pragma unroll
    for (int ni = 0; ni < 4; ++ni) {
      int gc = bn * 128 + wn * 64 + ni * 16 + lr;
      float bv = bias[gc];
#pragma unroll
      for (int r = 0; r < 4; ++r) {
        int gr = bm * 128 + wm * 64 + mi * 16 + lh * 4 + r;
        float v = acc[mi][ni][r] + bv;
        if (MODE == 0) {
          f16* x = (f16*)Cv;
          int b = gr >> 10, s = gr & 1023, h = gc >> 6, f = gc & 63;
          x[(size_t)((b * NH + h) * NS + s) * NF + f] = (f16)v;
        } else {
          ((float*)Cv)[(size_t)gr * DM + gc] = v;
        }
      }
    }
}

// ---------------------------------------------------------------------------
// transx: xT[bh][f][s] = x[bh][s][f]  (raw values, for PV V-fragments)
// ---------------------------------------------------------------------------
__global__ __launch_bounds__(256) void transx_kernel(const f16* __restrict__ x, f16* __restrict__ xT) {
  __shared__ f16 T[64][64];
  int bh = blockIdx.x >> 4, s0 = (blockIdx.x & 15) * 64;
  int tid = threadIdx.x;
  const f16* xb = x + (size_t)bh * (NS * NF);
#pragma unroll
  for (int it = 0; it < 2; ++it) {
    int idx = it * 256 + tid;
    int sr = idx >> 3, fcb = idx & 7;
    half8 v = *(const half8*)(xb + (size_t)(s0 + sr) * NF + fcb * 8);
    *(half8*)&T[sr][((fcb ^ ((sr >> 3) & 7)) * 8)] = v;
  }
  __syncthreads();
#pragma unroll
  for (int it = 0; it < 2; ++it) {
    int idx = it * 256 + tid;
    int fr = idx >> 3, scb = idx & 7;
    half8 v;
#pragma unroll
    for (int j = 0; j < 8; ++j) v[j] = T[scb * 8 + j][(((fr >> 3) ^ scb) * 8) + (fr & 7)];
    *(half8*)(xT + ((size_t)bh * NF + fr) * NS + s0 + scb * 8) = v;
  }
}

// ---------------------------------------------------------------------------
// normx: x <- x / ||x_row||  in place (rows of 64 f16; 4 lanes per row)
// ---------------------------------------------------------------------------
__global__ __launch_bounds__(256) void normx_kernel(f16* __restrict__ x) {
  int gid = blockIdx.x * 256 + threadIdx.x;
  int row = gid >> 2, sub = gid & 3;
  f16* p = x + (size_t)row * NF + sub * 16;
  half8 a = *(const half8*)p;
  half8 b = *(const half8*)(p + 8);
  float ss = 0.f;
#pragma unroll
  for (int i = 0; i < 8; ++i) {
    float u = (float)a[i], w = (float)b[i];
    ss += u * u + w * w;
  }
  ss += __shfl_xor(ss, 1, 64);
  ss += __shfl_xor(ss, 2, 64);
  float inv = rsqrtf(ss);
  half8 an, bn;
#pragma unroll
  for (int i = 0; i < 8; ++i) {
    an[i] = (f16)((float)a[i] * inv);
    bn[i] = (f16)((float)b[i] * inv);
  }
  *(half8*)p = an;
  *(half8*)(p + 8) = bn;
}

// ---------------------------------------------------------------------------
// attn v4: LDS-free, 32x32x16 MFMA, swapped QK^T, in-register softmax.
// XCD-grouped swizzle: all 8 q-tiles of one bh pinned to one XCD so its
// 256KB K/V working set stays in that XCD's L2 (16 bh x 256KB = 4MB = L2).
// V loads hoisted above the exp chain to overlap VALU with memory.
// ---------------------------------------------------------------------------
__global__ __launch_bounds__(256) void attn_kernel(const f16* __restrict__ xn, const f16* __restrict__ xT,
                                                   f16* __restrict__ ao) {
  int tid = threadIdx.x;
  int l = tid & 63, wv = tid >> 6;
  int lq = l & 31, hi = l >> 5;
  int kq = hi * 8;
  // XCD swizzle: bh % 8 == XCD, q-tile index from the k-slot
  int xcd = blockIdx.x & 7, m = blockIdx.x >> 3;
  int bh = ((m >> 3) << 3) | xcd;
  int q0 = (m & 7) * 128;
  const f16* xnb = xn + (size_t)bh * (NS * NF);
  const f16* xTb = xT + (size_t)bh * (NF * NS);

  int q = q0 + wv * 32 + lq;

  // Q fragments (B-operand of S^T): col = q, k = f
  half8 bq[4];
#pragma unroll
  for (int ks = 0; ks < 4; ++ks)
    bq[ks] = *(const half8*)(xnb + (size_t)q * NF + ks * 16 + kq);

  f32x16 accO[2];
  accO[0] = (f32x16)0.f;
  accO[1] = (f32x16)0.f;
  float rs = 0.f;

  for (int t0 = 0; t0 < NS; t0 += 128) {
#pragma unroll
    for (int ti = 0; ti < 4; ++ti) {
      // ---- issue all global loads for this tile up front ----
      half8 ak[4];
      int tr = t0 + ti * 32 + lq;
#pragma unroll
      for (int ks = 0; ks < 4; ++ks)
        ak[ks] = *(const half8*)(xnb + (size_t)tr * NF + ks * 16 + kq);
      half8 vbl[2][2];
#pragma unroll
      for (int sub = 0; sub < 2; ++sub)
#pragma unroll
        for (int ni = 0; ni < 2; ++ni)
          vbl[sub][ni] = *(const half8*)(xTb + (size_t)(ni * 32 + lq) * NS + t0 + ti * 32 + sub * 16 + kq);

      // ---- S^T[t-tile 32][q-tile 32] ----
      f32x16 sa = (f32x16)0.f;
#pragma unroll
      for (int ks = 0; ks < 4; ++ks)
        sa = __builtin_amdgcn_mfma_f32_32x32x16_f16(ak[ks], bq[ks], sa, 0, 0, 0);

      // ---- exp(s-1) with ==0 quirk; pack to f16 pairs (consecutive t) ----
      u32 pk[8];
#pragma unroll
      for (int mm = 0; mm < 8; ++mm) {
        float a = sa[2 * mm], b = sa[2 * mm + 1];
        float ea = (a == 0.f) ? 0.f : __expf(a - 1.f);
        float eb = (b == 0.f) ? 0.f : __expf(b - 1.f);
        rs += ea + eb;
        auto h = __builtin_amdgcn_cvt_pkrtz(ea, eb);
        pk[mm] = __builtin_bit_cast(u32, h);
      }
      // ---- redistribute P into PV A-fragments (partner = lane ^ 32) ----
      u32 sw[8];
#pragma unroll
      for (int mm = 0; mm < 8; ++mm) sw[mm] = (u32)__shfl_xor((int)pk[mm], 32, 64);
      bool lo = (hi == 0);
      uint4 a0, a1;
      a0.x = lo ? pk[0] : sw[2];
      a0.y = lo ? pk[1] : sw[3];
      a0.z = lo ? sw[0] : pk[2];
      a0.w = lo ? sw[1] : pk[3];
      a1.x = lo ? pk[4] : sw[6];
      a1.y = lo ? pk[5] : sw[7];
      a1.z = lo ? sw[4] : pk[6];
      a1.w = lo ? sw[5] : pk[7];
      half8 pa0 = __builtin_bit_cast(half8, a0);
      half8 pa1 = __builtin_bit_cast(half8, a1);
      // ---- PV: O[q][f] += P[q][t] * V[t][f] over this 32-t tile ----
#pragma unroll
      for (int sub = 0; sub < 2; ++sub) {
        half8 pa = sub ? pa1 : pa0;
#pragma unroll
        for (int ni = 0; ni < 2; ++ni)
          accO[ni] = __builtin_amdgcn_mfma_f32_32x32x16_f16(pa, vbl[sub][ni], accO[ni], 0, 0, 0);
      }
    }
  }

  // rowsum: lane and its partner (lane^32) hold complementary t-subsets of q=lq
  rs += __shfl_xor(rs, 32, 64);

  int b = bh >> 4, h = bh & 15;
#pragma unroll
  for (int r = 0; r < 16; ++r) {
    int qoff = (r & 3) + 8 * (r >> 2) + 4 * hi;
    float rv = __shfl(rs, qoff, 64);  // rs_total for q-row qoff lives at lane qoff
    float rinv = 1.0f / rv;
    int qg = q0 + wv * 32 + qoff;
#pragma unroll
    for (int ni = 0; ni < 2; ++ni) {
      int f = ni * 32 + lq;
      ao[((size_t)(b * NS + qg)) * DM + h * NF + f] = (f16)(accO[ni][r] * rinv);
    }
  }
}

extern "C" void kernel_launch(void* const* d_in, const int* in_sizes, int n_in,
                              void* d_out, int out_size, void* d_ws, size_t ws_size,
                              hipStream_t stream) {
  const float* sin_in = (const float*)d_in[0];
  // d_in[1] = mask (presence-only in reference)
  const float* Wx = (const float*)d_in[2];
  const float* bx = (const float*)d_in[3];
  const float* Wp = (const float*)d_in[4];
  const float* bp = (const float*)d_in[5];
  float* out = (float*)d_out;

  char* p = (char*)d_ws;
  f16* sinb = (f16*)p;                      p += (size_t)NB * NS * DM * 2;      // also reused as ao
  f16* x    = (f16*)p;                      p += (size_t)NB * NH * NS * NF * 2; // normalized in place
  f16* xT   = (f16*)p;                      p += (size_t)NB * NH * NF * NS * 2;
  f16* W2T  = (f16*)p;                      p += (size_t)DM * DM * 2;
  f16* WpT  = (f16*)p;                      p += (size_t)DM * DM * 2;
  f16* ao   = sinb;  // sinb dead after gemm<0>

  csin_kernel<<<4096, 256, 0, stream>>>(sin_in, sinb);
  cwx_kernel<<<512, 256, 0, stream>>>(Wx, W2T);
  cwp_kernel<<<512, 256, 0, stream>>>(Wp, WpT);
  gemm_kernel<0><<<512, 256, 0, stream>>>(sinb, W2T, bx, (void*)x);
  transx_kernel<<<2048, 256, 0, stream>>>(x, xT);   // raw V, transposed
  normx_kernel<<<2048, 256, 0, stream>>>(x);        // x -> x/||x|| in place
  attn_kernel<<<1024, 256, 0, stream>>>(x, xT, ao);
  gemm_kernel<1><<<512, 256, 0, stream>>>(ao, WpT, bp, (void*)out);
}

// Round 8
// 243.126 us; speedup vs baseline: 1.2312x; 1.2148x over previous
//
#include <hip/hip_runtime.h>
#include <hip/hip_bf16.h>
#include <math.h>

typedef _Float16 f16;
typedef _Float16 half8 __attribute__((ext_vector_type(8)));
typedef float f32x4 __attribute__((ext_vector_type(4)));
typedef float f32x16 __attribute__((ext_vector_type(16)));
typedef unsigned int u32;

#define NB 8
#define NS 1024
#define DM 1024
#define NH 16
#define NF 64

// ---------------------------------------------------------------------------
// convert sin f32 -> f16 (8 elems/thread)
// ---------------------------------------------------------------------------
__global__ __launch_bounds__(256) void csin_kernel(const float* __restrict__ in, f16* __restrict__ out) {
  long gid = (long)blockIdx.x * 256 + threadIdx.x;
  const float4* p = (const float4*)(in + gid * 8);
  float4 a = p[0], b = p[1];
  half8 v;
  v[0] = (f16)a.x; v[1] = (f16)a.y; v[2] = (f16)a.z; v[3] = (f16)a.w;
  v[4] = (f16)b.x; v[5] = (f16)b.y; v[6] = (f16)b.z; v[7] = (f16)b.w;
  *(half8*)(out + gid * 8) = v;
}

// ---------------------------------------------------------------------------
// cwx: W2T[h*64+f][d] = Wx[h][d][f] via LDS-tiled 64x64 transpose.
// ---------------------------------------------------------------------------
__global__ __launch_bounds__(256) void cwx_kernel(const float* __restrict__ Wx, f16* __restrict__ W2T) {
  __shared__ float T[64][65];
  int h = blockIdx.x >> 4, d0 = (blockIdx.x & 15) * 64;
  int tid = threadIdx.x;
  const float* src = Wx + ((size_t)h * 1024 + d0) * 64;
  int row = tid >> 2, cg = (tid & 3) * 16;
#pragma unroll
  for (int k = 0; k < 4; ++k) {
    float4 v = *(const float4*)(src + (size_t)row * 64 + cg + k * 4);
    T[row][cg + k * 4 + 0] = v.x;
    T[row][cg + k * 4 + 1] = v.y;
    T[row][cg + k * 4 + 2] = v.z;
    T[row][cg + k * 4 + 3] = v.w;
  }
  __syncthreads();
  int f = tid >> 2, dg = (tid & 3) * 16;
  f16 o[16];
#pragma unroll
  for (int j = 0; j < 16; ++j) o[j] = (f16)T[dg + j][f];
  *(half8*)(W2T + (size_t)(h * 64 + f) * DM + d0 + dg) = *(half8*)&o[0];
  *(half8*)(W2T + (size_t)(h * 64 + f) * DM + d0 + dg + 8) = *(half8*)&o[8];
}

// ---------------------------------------------------------------------------
// cwp: WpT[n][d] = Wp[d][n] via LDS-tiled 64x64 transpose.
// ---------------------------------------------------------------------------
__global__ __launch_bounds__(256) void cwp_kernel(const float* __restrict__ Wp, f16* __restrict__ WpT) {
  __shared__ float T[64][65];
  int n0 = (blockIdx.x >> 4) * 64, d0 = (blockIdx.x & 15) * 64;
  int tid = threadIdx.x;
  int row = tid >> 2, cg = (tid & 3) * 16;  // row = d-offset
#pragma unroll
  for (int k = 0; k < 4; ++k) {
    float4 v = *(const float4*)(Wp + (size_t)(d0 + row) * DM + n0 + cg + k * 4);
    T[row][cg + k * 4 + 0] = v.x;
    T[row][cg + k * 4 + 1] = v.y;
    T[row][cg + k * 4 + 2] = v.z;
    T[row][cg + k * 4 + 3] = v.w;
  }
  __syncthreads();
  int f = tid >> 2, dg = (tid & 3) * 16;  // f = n-offset
  f16 o[16];
#pragma unroll
  for (int j = 0; j < 16; ++j) o[j] = (f16)T[dg + j][f];
  *(half8*)(WpT + (size_t)(n0 + f) * DM + d0 + dg) = *(half8*)&o[0];
  *(half8*)(WpT + (size_t)(n0 + f) * DM + d0 + dg + 8) = *(half8*)&o[8];
}

// ---------------------------------------------------------------------------
// GEMM: C[8192,1024] = A @ Bt^T + bias. 128x128 tile, BK=64,
// linear LDS + global_load_lds width 16, XCD-grouped block swizzle.
// ---------------------------------------------------------------------------
template <int MODE>
__global__ __launch_bounds__(256) void gemm_kernel(const f16* __restrict__ A, const f16* __restrict__ Bt,
                                                   const float* __restrict__ bias, void* __restrict__ Cv) {
  __shared__ f16 As[128][64];
  __shared__ f16 Bs[128][64];
  int tid = threadIdx.x;
  int l = tid & 63, wv = tid >> 6;
  int wm = wv >> 1, wn = wv & 1;
  int xcd = blockIdx.x & 7, m = blockIdx.x >> 3;
  int bm = ((m >> 3) << 3) | xcd;  // bm % 8 == xcd
  int bn = m & 7;
  int lr = l & 15, lh = l >> 4;

  f32x4 acc[4][4];
#pragma unroll
  for (int i = 0; i < 4; ++i)
#pragma unroll
    for (int j = 0; j < 4; ++j) acc[i][j] = (f32x4)0.f;

  const f16* gA = A + (size_t)(bm * 128 + wv * 32 + (l >> 3)) * DM + (l & 7) * 8;
  const f16* gB = Bt + (size_t)(bn * 128 + wv * 32 + (l >> 3)) * DM + (l & 7) * 8;
  f16* ldsA = &As[wv * 32][0];
  f16* ldsB = &Bs[wv * 32][0];

  for (int k0 = 0; k0 < DM; k0 += 64) {
    __syncthreads();
#pragma unroll
    for (int c = 0; c < 4; ++c) {
      __builtin_amdgcn_global_load_lds(
          (const __attribute__((address_space(1))) void*)(gA + k0 + (size_t)c * 8 * DM),
          (__attribute__((address_space(3))) void*)(ldsA + c * 512), 16, 0, 0);
      __builtin_amdgcn_global_load_lds(
          (const __attribute__((address_space(1))) void*)(gB + k0 + (size_t)c * 8 * DM),
          (__attribute__((address_space(3))) void*)(ldsB + c * 512), 16, 0, 0);
    }
    __syncthreads();
#pragma unroll
    for (int ks = 0; ks < 2; ++ks) {
      half8 af[4], bf[4];
#pragma unroll
      for (int mi = 0; mi < 4; ++mi) af[mi] = *(const half8*)&As[wm * 64 + mi * 16 + lr][ks * 32 + lh * 8];
#pragma unroll
      for (int ni = 0; ni < 4; ++ni) bf[ni] = *(const half8*)&Bs[wn * 64 + ni * 16 + lr][ks * 32 + lh * 8];
#pragma unroll
      for (int mi = 0; mi < 4; ++mi)
#pragma unroll
        for (int ni = 0; ni < 4; ++ni)
          acc[mi][ni] = __builtin_amdgcn_mfma_f32_16x16x32_f16(af[mi], bf[ni], acc[mi][ni], 0, 0, 0);
    }
  }

#pragma unroll
  for (int mi = 0; mi < 4; ++mi)
#pragma unroll
    for (int ni = 0; ni < 4; ++ni) {
      int gc = bn * 128 + wn * 64 + ni * 16 + lr;
      float bv = bias[gc];
#pragma unroll
      for (int r = 0; r < 4; ++r) {
        int gr = bm * 128 + wm * 64 + mi * 16 + lh * 4 + r;
        float v = acc[mi][ni][r] + bv;
        if (MODE == 0) {
          f16* x = (f16*)Cv;
          int b = gr >> 10, s = gr & 1023, h = gc >> 6, f = gc & 63;
          x[(size_t)((b * NH + h) * NS + s) * NF + f] = (f16)v;
        } else {
          ((float*)Cv)[(size_t)gr * DM + gc] = v;
        }
      }
    }
}

// ---------------------------------------------------------------------------
// transnorm: one pass over x per 64-row tile:
//   - xT[bh][f][s] = x[bh][s][f] (raw, for PV V-fragments)
//   - x <- x / ||x_row||  in place (Q/K operands)
// ---------------------------------------------------------------------------
__global__ __launch_bounds__(256) void transnorm_kernel(f16* __restrict__ x, f16* __restrict__ xT) {
  __shared__ f16 T[64][64];
  __shared__ float sinv[64];
  int bh = blockIdx.x >> 4, s0 = (blockIdx.x & 15) * 64;
  int tid = threadIdx.x;
  f16* xb = x + (size_t)bh * (NS * NF);
  half8 vv[2];
#pragma unroll
  for (int it = 0; it < 2; ++it) {
    int idx = it * 256 + tid;
    int sr = idx >> 3, fcb = idx & 7;
    half8 v = *(const half8*)(xb + (size_t)(s0 + sr) * NF + fcb * 8);
    vv[it] = v;
    *(half8*)&T[sr][((fcb ^ ((sr >> 3) & 7)) * 8)] = v;
    float s = 0.f;
#pragma unroll
    for (int j = 0; j < 8; ++j) {
      float u = (float)v[j];
      s += u * u;
    }
    s += __shfl_xor(s, 1, 64);
    s += __shfl_xor(s, 2, 64);
    s += __shfl_xor(s, 4, 64);
    if ((tid & 7) == 0) sinv[sr] = rsqrtf(s);
  }
  __syncthreads();
  // write xT (raw values)
#pragma unroll
  for (int it = 0; it < 2; ++it) {
    int idx = it * 256 + tid;
    int fr = idx >> 3, scb = idx & 7;
    half8 v;
#pragma unroll
    for (int j = 0; j < 8; ++j) v[j] = T[scb * 8 + j][(((fr >> 3) ^ scb) * 8) + (fr & 7)];
    *(half8*)(xT + ((size_t)bh * NF + fr) * NS + s0 + scb * 8) = v;
  }
  // rewrite x normalized (reuse registers, coalesced same addresses)
#pragma unroll
  for (int it = 0; it < 2; ++it) {
    int idx = it * 256 + tid;
    int sr = idx >> 3, fcb = idx & 7;
    float inv = sinv[sr];
    half8 v = vv[it], o;
#pragma unroll
    for (int j = 0; j < 8; ++j) o[j] = (f16)((float)v[j] * inv);
    *(half8*)(xb + (size_t)(s0 + sr) * NF + fcb * 8) = o;
  }
}

// ---------------------------------------------------------------------------
// attn v5: LDS-free, 32x32x16 MFMA, swapped QK^T, in-register softmax.
// Each wave covers 64 q (2 subtiles) -> K/V fragments loaded once per tile
// feed 2x the MFMA (doubled arithmetic intensity vs v4).
// XCD-grouped swizzle: the 4 q-blocks of one bh pinned to one XCD.
// ---------------------------------------------------------------------------
__global__ __launch_bounds__(256) void attn_kernel(const f16* __restrict__ xn, const f16* __restrict__ xT,
                                                   f16* __restrict__ ao) {
  int tid = threadIdx.x;
  int l = tid & 63, wv = tid >> 6;
  int lq = l & 31, hi = l >> 5;
  int kq = hi * 8;
  int xcd = blockIdx.x & 7, m = blockIdx.x >> 3;
  int bh = ((m >> 2) << 3) | xcd;  // bh % 8 == xcd
  int q0 = (m & 3) * 256;
  const f16* xnb = xn + (size_t)bh * (NS * NF);
  const f16* xTb = xT + (size_t)bh * (NF * NS);

  // Q fragments (B-operand of S^T): col = q, k = f
  half8 bq[2][4];
#pragma unroll
  for (int qs = 0; qs < 2; ++qs)
#pragma unroll
    for (int ks = 0; ks < 4; ++ks)
      bq[qs][ks] = *(const half8*)(xnb + (size_t)(q0 + wv * 64 + qs * 32 + lq) * NF + ks * 16 + kq);

  f32x16 accO[2][2];
  accO[0][0] = (f32x16)0.f;
  accO[0][1] = (f32x16)0.f;
  accO[1][0] = (f32x16)0.f;
  accO[1][1] = (f32x16)0.f;
  float rs[2] = {0.f, 0.f};

  for (int t0 = 0; t0 < NS; t0 += 128) {
#pragma unroll
    for (int ti = 0; ti < 4; ++ti) {
      // ---- shared K/V loads for this 32-t tile (reused by both q-subtiles) ----
      half8 ak[4];
      int tr = t0 + ti * 32 + lq;
#pragma unroll
      for (int ks = 0; ks < 4; ++ks)
        ak[ks] = *(const half8*)(xnb + (size_t)tr * NF + ks * 16 + kq);
      half8 vbl[2][2];
#pragma unroll
      for (int sub = 0; sub < 2; ++sub)
#pragma unroll
        for (int ni = 0; ni < 2; ++ni)
          vbl[sub][ni] = *(const half8*)(xTb + (size_t)(ni * 32 + lq) * NS + t0 + ti * 32 + sub * 16 + kq);

#pragma unroll
      for (int qs = 0; qs < 2; ++qs) {
        // ---- S^T[t 32][q 32] ----
        f32x16 sa = (f32x16)0.f;
#pragma unroll
        for (int ks = 0; ks < 4; ++ks)
          sa = __builtin_amdgcn_mfma_f32_32x32x16_f16(ak[ks], bq[qs][ks], sa, 0, 0, 0);

        // ---- exp(s-1) with ==0 quirk; pack to f16 pairs (consecutive t) ----
        u32 pk[8];
#pragma unroll
        for (int mm = 0; mm < 8; ++mm) {
          float a = sa[2 * mm], b = sa[2 * mm + 1];
          float ea = (a == 0.f) ? 0.f : __expf(a - 1.f);
          float eb = (b == 0.f) ? 0.f : __expf(b - 1.f);
          rs[qs] += ea + eb;
          auto h = __builtin_amdgcn_cvt_pkrtz(ea, eb);
          pk[mm] = __builtin_bit_cast(u32, h);
        }
        // ---- redistribute P into PV A-fragments (partner = lane ^ 32) ----
        u32 sw[8];
#pragma unroll
        for (int mm = 0; mm < 8; ++mm) sw[mm] = (u32)__shfl_xor((int)pk[mm], 32, 64);
        bool lo = (hi == 0);
        uint4 a0, a1;
        a0.x = lo ? pk[0] : sw[2];
        a0.y = lo ? pk[1] : sw[3];
        a0.z = lo ? sw[0] : pk[2];
        a0.w = lo ? sw[1] : pk[3];
        a1.x = lo ? pk[4] : sw[6];
        a1.y = lo ? pk[5] : sw[7];
        a1.z = lo ? sw[4] : pk[6];
        a1.w = lo ? sw[5] : pk[7];
        half8 pa0 = __builtin_bit_cast(half8, a0);
        half8 pa1 = __builtin_bit_cast(half8, a1);
        // ---- PV: O[q][f] += P[q][t] * V[t][f] over this 32-t tile ----
#pragma unroll
        for (int sub = 0; sub < 2; ++sub) {
          half8 pa = sub ? pa1 : pa0;
#pragma unroll
          for (int ni = 0; ni < 2; ++ni)
            accO[qs][ni] = __builtin_amdgcn_mfma_f32_32x32x16_f16(pa, vbl[sub][ni], accO[qs][ni], 0, 0, 0);
        }
      }
    }
  }

  rs[0] += __shfl_xor(rs[0], 32, 64);
  rs[1] += __shfl_xor(rs[1], 32, 64);

  int b = bh >> 4, h = bh & 15;
#pragma unroll
  for (int qs = 0; qs < 2; ++qs)
#pragma unroll
    for (int r = 0; r < 16; ++r) {
      int qoff = (r & 3) + 8 * (r >> 2) + 4 * hi;
      float rv = __shfl(rs[qs], qoff, 64);
      float rinv = 1.0f / rv;
      int qg = q0 + wv * 64 + qs * 32 + qoff;
#pragma unroll
      for (int ni = 0; ni < 2; ++ni) {
        int f = ni * 32 + lq;
        ao[((size_t)(b * NS + qg)) * DM + h * NF + f] = (f16)(accO[qs][ni][r] * rinv);
      }
    }
}

extern "C" void kernel_launch(void* const* d_in, const int* in_sizes, int n_in,
                              void* d_out, int out_size, void* d_ws, size_t ws_size,
                              hipStream_t stream) {
  const float* sin_in = (const float*)d_in[0];
  // d_in[1] = mask (presence-only in reference)
  const float* Wx = (const float*)d_in[2];
  const float* bx = (const float*)d_in[3];
  const float* Wp = (const float*)d_in[4];
  const float* bp = (const float*)d_in[5];
  float* out = (float*)d_out;

  char* p = (char*)d_ws;
  f16* sinb = (f16*)p;                      p += (size_t)NB * NS * DM * 2;      // also reused as ao
  f16* x    = (f16*)p;                      p += (size_t)NB * NH * NS * NF * 2; // normalized in place
  f16* xT   = (f16*)p;                      p += (size_t)NB * NH * NF * NS * 2;
  f16* W2T  = (f16*)p;                      p += (size_t)DM * DM * 2;
  f16* WpT  = (f16*)p;                      p += (size_t)DM * DM * 2;
  f16* ao   = sinb;  // sinb dead after gemm<0>

  csin_kernel<<<4096, 256, 0, stream>>>(sin_in, sinb);
  cwx_kernel<<<256, 256, 0, stream>>>(Wx, W2T);
  cwp_kernel<<<256, 256, 0, stream>>>(Wp, WpT);
  gemm_kernel<0><<<512, 256, 0, stream>>>(sinb, W2T, bx, (void*)x);
  transnorm_kernel<<<2048, 256, 0, stream>>>(x, xT);  // xT raw + x normalized
  attn_kernel<<<512, 256, 0, stream>>>(x, xT, ao);
  gemm_kernel<1><<<512, 256, 0, stream>>>(ao, WpT, bp, (void*)out);
}

// Round 10
// 236.976 us; speedup vs baseline: 1.2632x; 1.0260x over previous
//
#include <hip/hip_runtime.h>
#include <hip/hip_bf16.h>
#include <math.h>

typedef _Float16 f16;
typedef _Float16 half8 __attribute__((ext_vector_type(8)));
typedef float f32x4 __attribute__((ext_vector_type(4)));
typedef float f32x16 __attribute__((ext_vector_type(16)));
typedef unsigned int u32;

#define NB 8
#define NS 1024
#define DM 1024
#define NH 16
#define NF 64

// ---------------------------------------------------------------------------
// convert sin f32 -> f16 (8 elems/thread)
// ---------------------------------------------------------------------------
__global__ __launch_bounds__(256) void csin_kernel(const float* __restrict__ in, f16* __restrict__ out) {
  long gid = (long)blockIdx.x * 256 + threadIdx.x;
  const float4* p = (const float4*)(in + gid * 8);
  float4 a = p[0], b = p[1];
  half8 v;
  v[0] = (f16)a.x; v[1] = (f16)a.y; v[2] = (f16)a.z; v[3] = (f16)a.w;
  v[4] = (f16)b.x; v[5] = (f16)b.y; v[6] = (f16)b.z; v[7] = (f16)b.w;
  *(half8*)(out + gid * 8) = v;
}

// ---------------------------------------------------------------------------
// cwx: W2T[h*64+f][d] = Wx[h][d][f] via LDS-tiled 64x64 transpose.
// ---------------------------------------------------------------------------
__global__ __launch_bounds__(256) void cwx_kernel(const float* __restrict__ Wx, f16* __restrict__ W2T) {
  __shared__ float T[64][65];
  int h = blockIdx.x >> 4, d0 = (blockIdx.x & 15) * 64;
  int tid = threadIdx.x;
  const float* src = Wx + ((size_t)h * 1024 + d0) * 64;
  int row = tid >> 2, cg = (tid & 3) * 16;
#pragma unroll
  for (int k = 0; k < 4; ++k) {
    float4 v = *(const float4*)(src + (size_t)row * 64 + cg + k * 4);
    T[row][cg + k * 4 + 0] = v.x;
    T[row][cg + k * 4 + 1] = v.y;
    T[row][cg + k * 4 + 2] = v.z;
    T[row][cg + k * 4 + 3] = v.w;
  }
  __syncthreads();
  int f = tid >> 2, dg = (tid & 3) * 16;
  f16 o[16];
#pragma unroll
  for (int j = 0; j < 16; ++j) o[j] = (f16)T[dg + j][f];
  *(half8*)(W2T + (size_t)(h * 64 + f) * DM + d0 + dg) = *(half8*)&o[0];
  *(half8*)(W2T + (size_t)(h * 64 + f) * DM + d0 + dg + 8) = *(half8*)&o[8];
}

// ---------------------------------------------------------------------------
// cwp: WpT[n][d] = Wp[d][n] via LDS-tiled 64x64 transpose.
// ---------------------------------------------------------------------------
__global__ __launch_bounds__(256) void cwp_kernel(const float* __restrict__ Wp, f16* __restrict__ WpT) {
  __shared__ float T[64][65];
  int n0 = (blockIdx.x >> 4) * 64, d0 = (blockIdx.x & 15) * 64;
  int tid = threadIdx.x;
  int row = tid >> 2, cg = (tid & 3) * 16;
#pragma unroll
  for (int k = 0; k < 4; ++k) {
    float4 v = *(const float4*)(Wp + (size_t)(d0 + row) * DM + n0 + cg + k * 4);
    T[row][cg + k * 4 + 0] = v.x;
    T[row][cg + k * 4 + 1] = v.y;
    T[row][cg + k * 4 + 2] = v.z;
    T[row][cg + k * 4 + 3] = v.w;
  }
  __syncthreads();
  int f = tid >> 2, dg = (tid & 3) * 16;
  f16 o[16];
#pragma unroll
  for (int j = 0; j < 16; ++j) o[j] = (f16)T[dg + j][f];
  *(half8*)(WpT + (size_t)(n0 + f) * DM + d0 + dg) = *(half8*)&o[0];
  *(half8*)(WpT + (size_t)(n0 + f) * DM + d0 + dg + 8) = *(half8*)&o[8];
}

// ---------------------------------------------------------------------------
// GEMM: C[8192,1024] = A @ Bt^T + bias. 128x128 tile, BK=64,
// linear LDS + global_load_lds width 16, XCD-grouped block swizzle.
// ---------------------------------------------------------------------------
template <int MODE>
__global__ __launch_bounds__(256) void gemm_kernel(const f16* __restrict__ A, const f16* __restrict__ Bt,
                                                   const float* __restrict__ bias, void* __restrict__ Cv) {
  __shared__ f16 As[128][64];
  __shared__ f16 Bs[128][64];
  int tid = threadIdx.x;
  int l = tid & 63, wv = tid >> 6;
  int wm = wv >> 1, wn = wv & 1;
  int xcd = blockIdx.x & 7, m = blockIdx.x >> 3;
  int bm = ((m >> 3) << 3) | xcd;  // bm % 8 == xcd
  int bn = m & 7;
  int lr = l & 15, lh = l >> 4;

  f32x4 acc[4][4];
#pragma unroll
  for (int i = 0; i < 4; ++i)
#pragma unroll
    for (int j = 0; j < 4; ++j) acc[i][j] = (f32x4)0.f;

  const f16* gA = A + (size_t)(bm * 128 + wv * 32 + (l >> 3)) * DM + (l & 7) * 8;
  const f16* gB = Bt + (size_t)(bn * 128 + wv * 32 + (l >> 3)) * DM + (l & 7) * 8;
  f16* ldsA = &As[wv * 32][0];
  f16* ldsB = &Bs[wv * 32][0];

  for (int k0 = 0; k0 < DM; k0 += 64) {
    __syncthreads();
#pragma unroll
    for (int c = 0; c < 4; ++c) {
      __builtin_amdgcn_global_load_lds(
          (const __attribute__((address_space(1))) void*)(gA + k0 + (size_t)c * 8 * DM),
          (__attribute__((address_space(3))) void*)(ldsA + c * 512), 16, 0, 0);
      __builtin_amdgcn_global_load_lds(
          (const __attribute__((address_space(1))) void*)(gB + k0 + (size_t)c * 8 * DM),
          (__attribute__((address_space(3))) void*)(ldsB + c * 512), 16, 0, 0);
    }
    __syncthreads();
#pragma unroll
    for (int ks = 0; ks < 2; ++ks) {
      half8 af[4], bf[4];
#pragma unroll
      for (int mi = 0; mi < 4; ++mi) af[mi] = *(const half8*)&As[wm * 64 + mi * 16 + lr][ks * 32 + lh * 8];
#pragma unroll
      for (int ni = 0; ni < 4; ++ni) bf[ni] = *(const half8*)&Bs[wn * 64 + ni * 16 + lr][ks * 32 + lh * 8];
#pragma unroll
      for (int mi = 0; mi < 4; ++mi)
#pragma unroll
        for (int ni = 0; ni < 4; ++ni)
          acc[mi][ni] = __builtin_amdgcn_mfma_f32_16x16x32_f16(af[mi], bf[ni], acc[mi][ni], 0, 0, 0);
    }
  }

#pragma unroll
  for (int mi = 0; mi < 4; ++mi)
#pragma unroll
    for (int ni = 0; ni < 4; ++ni) {
      int gc = bn * 128 + wn * 64 + ni * 16 + lr;
      float bv = bias[gc];
#pragma unroll
      for (int r = 0; r < 4; ++r) {
        int gr = bm * 128 + wm * 64 + mi * 16 + lh * 4 + r;
        float v = acc[mi][ni][r] + bv;
        if (MODE == 0) {
          f16* x = (f16*)Cv;
          int b = gr >> 10, s = gr & 1023, h = gc >> 6, f = gc & 63;
          x[(size_t)((b * NH + h) * NS + s) * NF + f] = (f16)v;
        } else {
          ((float*)Cv)[(size_t)gr * DM + gc] = v;
        }
      }
    }
}

// ---------------------------------------------------------------------------
// transnorm: one pass over x per 64-row tile:
//   - xT[bh][f][s] = x[bh][s][f] (raw, for PV V-fragments)
//   - x <- x / ||x_row||  in place (Q/K operands)
// ---------------------------------------------------------------------------
__global__ __launch_bounds__(256) void transnorm_kernel(f16* __restrict__ x, f16* __restrict__ xT) {
  __shared__ f16 T[64][64];
  __shared__ float sinv[64];
  int bh = blockIdx.x >> 4, s0 = (blockIdx.x & 15) * 64;
  int tid = threadIdx.x;
  f16* xb = x + (size_t)bh * (NS * NF);
  half8 vv[2];
#pragma unroll
  for (int it = 0; it < 2; ++it) {
    int idx = it * 256 + tid;
    int sr = idx >> 3, fcb = idx & 7;
    half8 v = *(const half8*)(xb + (size_t)(s0 + sr) * NF + fcb * 8);
    vv[it] = v;
    *(half8*)&T[sr][((fcb ^ ((sr >> 3) & 7)) * 8)] = v;
    float s = 0.f;
#pragma unroll
    for (int j = 0; j < 8; ++j) {
      float u = (float)v[j];
      s += u * u;
    }
    s += __shfl_xor(s, 1, 64);
    s += __shfl_xor(s, 2, 64);
    s += __shfl_xor(s, 4, 64);
    if ((tid & 7) == 0) sinv[sr] = rsqrtf(s);
  }
  __syncthreads();
#pragma unroll
  for (int it = 0; it < 2; ++it) {
    int idx = it * 256 + tid;
    int fr = idx >> 3, scb = idx & 7;
    half8 v;
#pragma unroll
    for (int j = 0; j < 8; ++j) v[j] = T[scb * 8 + j][(((fr >> 3) ^ scb) * 8) + (fr & 7)];
    *(half8*)(xT + ((size_t)bh * NF + fr) * NS + s0 + scb * 8) = v;
  }
#pragma unroll
  for (int it = 0; it < 2; ++it) {
    int idx = it * 256 + tid;
    int sr = idx >> 3, fcb = idx & 7;
    float inv = sinv[sr];
    half8 v = vv[it], o;
#pragma unroll
    for (int j = 0; j < 8; ++j) o[j] = (f16)((float)v[j] * inv);
    *(half8*)(xb + (size_t)(s0 + sr) * NF + fcb * 8) = o;
  }
}

// ---------------------------------------------------------------------------
// attn v6: LDS double-buffered K/V staging shared by 4 waves (4x fewer L2
// loads vs v5), XOR-swizzled via pre-swizzled global source (linear LDS dest).
// 64 q per wave (2 subtiles), swapped QK^T, in-register softmax with fixed
// max=1 (cosine <= 1), permlane32_swap P-redistribution, exp2-form exp.
// Grid 512: bh%8 == XCD, 4 q-blocks (256 q) per bh.
// ---------------------------------------------------------------------------
__global__ __launch_bounds__(256) void attn_kernel(const f16* __restrict__ xn, const f16* __restrict__ xT,
                                                   f16* __restrict__ ao) {
  __shared__ f16 KB[2][2048];  // [buf][32 t][64 f], 16B-col XOR-swizzled by (row&7)
  __shared__ f16 VB[2][2048];  // [buf][64 f][32 t], 16B-col XOR-swizzled by (row&3)

  int tid = threadIdx.x;
  int l = tid & 63, wv = tid >> 6;
  int lq = l & 31, hi = l >> 5;
  int kq = hi * 8;
  int xcd = blockIdx.x & 7, m = blockIdx.x >> 3;
  int bh = ((m >> 2) << 3) | xcd;  // bh % 8 == xcd
  int q0 = (m & 3) * 256;
  const f16* xnb = xn + (size_t)bh * (NS * NF);
  const f16* xTb = xT + (size_t)bh * (NF * NS);

  // ---- staging source addresses (pre-swizzled so LDS dest is linear) ----
  int krow = wv * 8 + (l >> 3);
  const f16* gK0 = xnb + (size_t)krow * NF + (((l & 7) ^ (krow & 7)) * 8);
  int vrow = wv * 16 + (l >> 2);
  const f16* gV0 = xTb + (size_t)vrow * NS + (((l & 3) ^ (vrow & 3)) * 8);

  // ---- LDS read byte-offsets (constant per lane, buffer toggles +4096) ----
  int akoff[4], vboff[2][2];
#pragma unroll
  for (int ks = 0; ks < 4; ++ks)
    akoff[ks] = lq * 128 + ((((ks * 2 + hi)) ^ (lq & 7)) << 4);
#pragma unroll
  for (int sub = 0; sub < 2; ++sub)
#pragma unroll
    for (int ni = 0; ni < 2; ++ni) {
      int r = ni * 32 + lq;
      vboff[sub][ni] = r * 64 + (((sub * 2 + hi) ^ (r & 3)) << 4);
    }

  // Q fragments (B-operand of S^T): col = q, k = f
  half8 bq[2][4];
#pragma unroll
  for (int qs = 0; qs < 2; ++qs)
#pragma unroll
    for (int ks = 0; ks < 4; ++ks)
      bq[qs][ks] = *(const half8*)(xnb + (size_t)(q0 + wv * 64 + qs * 32 + lq) * NF + ks * 16 + kq);

  f32x16 accO[2][2];
  accO[0][0] = (f32x16)0.f;
  accO[0][1] = (f32x16)0.f;
  accO[1][0] = (f32x16)0.f;
  accO[1][1] = (f32x16)0.f;
  float rs[2] = {0.f, 0.f};

#define STAGE(buf, t0_)                                                                              \
  do {                                                                                               \
    __builtin_amdgcn_global_load_lds(                                                                \
        (const __attribute__((address_space(1))) void*)(gK0 + (size_t)(t0_) * NF),                   \
        (__attribute__((address_space(3))) void*)(&KB[buf][wv * 512]), 16, 0, 0);                    \
    __builtin_amdgcn_global_load_lds(                                                                \
        (const __attribute__((address_space(1))) void*)(gV0 + (t0_)),                                \
        (__attribute__((address_space(3))) void*)(&VB[buf][wv * 512]), 16, 0, 0);                    \
  } while (0)

  const float L2E = 1.4426950408889634f;

  STAGE(0, 0);
  asm volatile("s_waitcnt vmcnt(0)" ::: "memory");
  __syncthreads();

  int cur = 0;
  for (int t = 0; t < 32; ++t) {
    if (t < 31) STAGE(cur ^ 1, (t + 1) * 32);

    const char* kb = (const char*)&KB[cur][0];
    const char* vb = (const char*)&VB[cur][0];
    half8 ak[4];
#pragma unroll
    for (int ks = 0; ks < 4; ++ks) ak[ks] = *(const half8*)(kb + akoff[ks]);
    half8 vbl[2][2];
#pragma unroll
    for (int sub = 0; sub < 2; ++sub)
#pragma unroll
      for (int ni = 0; ni < 2; ++ni) vbl[sub][ni] = *(const half8*)(vb + vboff[sub][ni]);

#pragma unroll
    for (int qs = 0; qs < 2; ++qs) {
      // ---- S^T[t 32][q 32] ----
      f32x16 sa = (f32x16)0.f;
      __builtin_amdgcn_s_setprio(1);
#pragma unroll
      for (int ks = 0; ks < 4; ++ks)
        sa = __builtin_amdgcn_mfma_f32_32x32x16_f16(ak[ks], bq[qs][ks], sa, 0, 0, 0);
      __builtin_amdgcn_s_setprio(0);

      // ---- p = exp(s-1) = exp2(s*log2e - log2e), quirk: s==0 -> 0 ----
      u32 pk[8];
#pragma unroll
      for (int mm = 0; mm < 8; ++mm) {
        float a = sa[2 * mm], b = sa[2 * mm + 1];
        float ea = (a == 0.f) ? 0.f : exp2f(__builtin_fmaf(a, L2E, -L2E));
        float eb = (b == 0.f) ? 0.f : exp2f(__builtin_fmaf(b, L2E, -L2E));
        rs[qs] += ea + eb;
        auto h = __builtin_amdgcn_cvt_pkrtz(ea, eb);
        pk[mm] = __builtin_bit_cast(u32, h);
      }
      // ---- redistribute P into PV A-fragments ----
      uint4 a0, a1;
#if __has_builtin(__builtin_amdgcn_permlane32_swap)
      {
        auto s02 = __builtin_amdgcn_permlane32_swap((int)pk[0], (int)pk[2], false, false);
        auto s13 = __builtin_amdgcn_permlane32_swap((int)pk[1], (int)pk[3], false, false);
        auto s46 = __builtin_amdgcn_permlane32_swap((int)pk[4], (int)pk[6], false, false);
        auto s57 = __builtin_amdgcn_permlane32_swap((int)pk[5], (int)pk[7], false, false);
        a0.x = (u32)s02[0]; a0.z = (u32)s02[1];
        a0.y = (u32)s13[0]; a0.w = (u32)s13[1];
        a1.x = (u32)s46[0]; a1.z = (u32)s46[1];
        a1.y = (u32)s57[0]; a1.w = (u32)s57[1];
      }
#else
      {
        u32 sw[8];
#pragma unroll
        for (int mm = 0; mm < 8; ++mm) sw[mm] = (u32)__shfl_xor((int)pk[mm], 32, 64);
        bool lo = (hi == 0);
        a0.x = lo ? pk[0] : sw[2];
        a0.y = lo ? pk[1] : sw[3];
        a0.z = lo ? sw[0] : pk[2];
        a0.w = lo ? sw[1] : pk[3];
        a1.x = lo ? pk[4] : sw[6];
        a1.y = lo ? pk[5] : sw[7];
        a1.z = lo ? sw[4] : pk[6];
        a1.w = lo ? sw[5] : pk[7];
      }
#endif
      half8 pa0 = __builtin_bit_cast(half8, a0);
      half8 pa1 = __builtin_bit_cast(half8, a1);
      // ---- PV: O[q][f] += P[q][t] * V[t][f] over this 32-t tile ----
      __builtin_amdgcn_s_setprio(1);
#pragma unroll
      for (int sub = 0; sub < 2; ++sub) {
        half8 pa = sub ? pa1 : pa0;
#pragma unroll
        for (int ni = 0; ni < 2; ++ni)
          accO[qs][ni] = __builtin_amdgcn_mfma_f32_32x32x16_f16(pa, vbl[sub][ni], accO[qs][ni], 0, 0, 0);
      }
      __builtin_amdgcn_s_setprio(0);
    }

    asm volatile("s_waitcnt vmcnt(0)" ::: "memory");
    __syncthreads();
    cur ^= 1;
  }
#undef STAGE

  rs[0] += __shfl_xor(rs[0], 32, 64);
  rs[1] += __shfl_xor(rs[1], 32, 64);

  int b = bh >> 4, h = bh & 15;
#pragma unroll
  for (int qs = 0; qs < 2; ++qs)
#pragma unroll
    for (int r = 0; r < 16; ++r) {
      int qoff = (r & 3) + 8 * (r >> 2) + 4 * hi;
      float rv = __shfl(rs[qs], qoff, 64);
      float rinv = 1.0f / rv;
      int qg = q0 + wv * 64 + qs * 32 + qoff;
#pragma unroll
      for (int ni = 0; ni < 2; ++ni) {
        int f = ni * 32 + lq;
        ao[((size_t)(b * NS + qg)) * DM + h * NF + f] = (f16)(accO[qs][ni][r] * rinv);
      }
    }
}

extern "C" void kernel_launch(void* const* d_in, const int* in_sizes, int n_in,
                              void* d_out, int out_size, void* d_ws, size_t ws_size,
                              hipStream_t stream) {
  const float* sin_in = (const float*)d_in[0];
  // d_in[1] = mask (presence-only in reference)
  const float* Wx = (const float*)d_in[2];
  const float* bx = (const float*)d_in[3];
  const float* Wp = (const float*)d_in[4];
  const float* bp = (const float*)d_in[5];
  float* out = (float*)d_out;

  char* p = (char*)d_ws;
  f16* sinb = (f16*)p;                      p += (size_t)NB * NS * DM * 2;      // also reused as ao
  f16* x    = (f16*)p;                      p += (size_t)NB * NH * NS * NF * 2; // normalized in place
  f16* xT   = (f16*)p;                      p += (size_t)NB * NH * NF * NS * 2;
  f16* W2T  = (f16*)p;                      p += (size_t)DM * DM * 2;
  f16* WpT  = (f16*)p;                      p += (size_t)DM * DM * 2;
  f16* ao   = sinb;  // sinb dead after gemm<0>

  csin_kernel<<<4096, 256, 0, stream>>>(sin_in, sinb);
  cwx_kernel<<<256, 256, 0, stream>>>(Wx, W2T);
  cwp_kernel<<<256, 256, 0, stream>>>(Wp, WpT);
  gemm_kernel<0><<<512, 256, 0, stream>>>(sinb, W2T, bx, (void*)x);
  transnorm_kernel<<<2048, 256, 0, stream>>>(x, xT);  // xT raw + x normalized
  attn_kernel<<<512, 256, 0, stream>>>(x, xT, ao);
  gemm_kernel<1><<<512, 256, 0, stream>>>(ao, WpT, bp, (void*)out);
}

// Round 11
// 223.607 us; speedup vs baseline: 1.3387x; 1.0598x over previous
//
#include <hip/hip_runtime.h>
#include <hip/hip_bf16.h>
#include <math.h>

typedef _Float16 f16;
typedef _Float16 half8 __attribute__((ext_vector_type(8)));
typedef float f32x4 __attribute__((ext_vector_type(4)));
typedef float f32x16 __attribute__((ext_vector_type(16)));
typedef unsigned int u32;

#define NB 8
#define NS 1024
#define DM 1024
#define NH 16
#define NF 64

// ---------------------------------------------------------------------------
// convert sin f32 -> f16 (8 elems/thread)
// ---------------------------------------------------------------------------
__global__ __launch_bounds__(256) void csin_kernel(const float* __restrict__ in, f16* __restrict__ out) {
  long gid = (long)blockIdx.x * 256 + threadIdx.x;
  const float4* p = (const float4*)(in + gid * 8);
  float4 a = p[0], b = p[1];
  half8 v;
  v[0] = (f16)a.x; v[1] = (f16)a.y; v[2] = (f16)a.z; v[3] = (f16)a.w;
  v[4] = (f16)b.x; v[5] = (f16)b.y; v[6] = (f16)b.z; v[7] = (f16)b.w;
  *(half8*)(out + gid * 8) = v;
}

// ---------------------------------------------------------------------------
// cwx: W2T[h*64+f][d] = Wx[h][d][f] via LDS-tiled 64x64 transpose.
// ---------------------------------------------------------------------------
__global__ __launch_bounds__(256) void cwx_kernel(const float* __restrict__ Wx, f16* __restrict__ W2T) {
  __shared__ float T[64][65];
  int h = blockIdx.x >> 4, d0 = (blockIdx.x & 15) * 64;
  int tid = threadIdx.x;
  const float* src = Wx + ((size_t)h * 1024 + d0) * 64;
  int row = tid >> 2, cg = (tid & 3) * 16;
#pragma unroll
  for (int k = 0; k < 4; ++k) {
    float4 v = *(const float4*)(src + (size_t)row * 64 + cg + k * 4);
    T[row][cg + k * 4 + 0] = v.x;
    T[row][cg + k * 4 + 1] = v.y;
    T[row][cg + k * 4 + 2] = v.z;
    T[row][cg + k * 4 + 3] = v.w;
  }
  __syncthreads();
  int f = tid >> 2, dg = (tid & 3) * 16;
  f16 o[16];
#pragma unroll
  for (int j = 0; j < 16; ++j) o[j] = (f16)T[dg + j][f];
  *(half8*)(W2T + (size_t)(h * 64 + f) * DM + d0 + dg) = *(half8*)&o[0];
  *(half8*)(W2T + (size_t)(h * 64 + f) * DM + d0 + dg + 8) = *(half8*)&o[8];
}

// ---------------------------------------------------------------------------
// cwp: WpT[n][d] = Wp[d][n] via LDS-tiled 64x64 transpose.
// ---------------------------------------------------------------------------
__global__ __launch_bounds__(256) void cwp_kernel(const float* __restrict__ Wp, f16* __restrict__ WpT) {
  __shared__ float T[64][65];
  int n0 = (blockIdx.x >> 4) * 64, d0 = (blockIdx.x & 15) * 64;
  int tid = threadIdx.x;
  int row = tid >> 2, cg = (tid & 3) * 16;
#pragma unroll
  for (int k = 0; k < 4; ++k) {
    float4 v = *(const float4*)(Wp + (size_t)(d0 + row) * DM + n0 + cg + k * 4);
    T[row][cg + k * 4 + 0] = v.x;
    T[row][cg + k * 4 + 1] = v.y;
    T[row][cg + k * 4 + 2] = v.z;
    T[row][cg + k * 4 + 3] = v.w;
  }
  __syncthreads();
  int f = tid >> 2, dg = (tid & 3) * 16;
  f16 o[16];
#pragma unroll
  for (int j = 0; j < 16; ++j) o[j] = (f16)T[dg + j][f];
  *(half8*)(WpT + (size_t)(n0 + f) * DM + d0 + dg) = *(half8*)&o[0];
  *(half8*)(WpT + (size_t)(n0 + f) * DM + d0 + dg + 8) = *(half8*)&o[8];
}

// ---------------------------------------------------------------------------
// GEMM: C[8192,1024] = A @ Bt^T + bias. 128x128 tile, BK=64,
// linear LDS + global_load_lds width 16, XCD-grouped block swizzle.
// ---------------------------------------------------------------------------
template <int MODE>
__global__ __launch_bounds__(256) void gemm_kernel(const f16* __restrict__ A, const f16* __restrict__ Bt,
                                                   const float* __restrict__ bias, void* __restrict__ Cv) {
  __shared__ f16 As[128][64];
  __shared__ f16 Bs[128][64];
  int tid = threadIdx.x;
  int l = tid & 63, wv = tid >> 6;
  int wm = wv >> 1, wn = wv & 1;
  int xcd = blockIdx.x & 7, m = blockIdx.x >> 3;
  int bm = ((m >> 3) << 3) | xcd;  // bm % 8 == xcd
  int bn = m & 7;
  int lr = l & 15, lh = l >> 4;

  f32x4 acc[4][4];
#pragma unroll
  for (int i = 0; i < 4; ++i)
#pragma unroll
    for (int j = 0; j < 4; ++j) acc[i][j] = (f32x4)0.f;

  const f16* gA = A + (size_t)(bm * 128 + wv * 32 + (l >> 3)) * DM + (l & 7) * 8;
  const f16* gB = Bt + (size_t)(bn * 128 + wv * 32 + (l >> 3)) * DM + (l & 7) * 8;
  f16* ldsA = &As[wv * 32][0];
  f16* ldsB = &Bs[wv * 32][0];

  for (int k0 = 0; k0 < DM; k0 += 64) {
    __syncthreads();
#pragma unroll
    for (int c = 0; c < 4; ++c) {
      __builtin_amdgcn_global_load_lds(
          (const __attribute__((address_space(1))) void*)(gA + k0 + (size_t)c * 8 * DM),
          (__attribute__((address_space(3))) void*)(ldsA + c * 512), 16, 0, 0);
      __builtin_amdgcn_global_load_lds(
          (const __attribute__((address_space(1))) void*)(gB + k0 + (size_t)c * 8 * DM),
          (__attribute__((address_space(3))) void*)(ldsB + c * 512), 16, 0, 0);
    }
    __syncthreads();
#pragma unroll
    for (int ks = 0; ks < 2; ++ks) {
      half8 af[4], bf[4];
#pragma unroll
      for (int mi = 0; mi < 4; ++mi) af[mi] = *(const half8*)&As[wm * 64 + mi * 16 + lr][ks * 32 + lh * 8];
#pragma unroll
      for (int ni = 0; ni < 4; ++ni) bf[ni] = *(const half8*)&Bs[wn * 64 + ni * 16 + lr][ks * 32 + lh * 8];
#pragma unroll
      for (int mi = 0; mi < 4; ++mi)
#pragma unroll
        for (int ni = 0; ni < 4; ++ni)
          acc[mi][ni] = __builtin_amdgcn_mfma_f32_16x16x32_f16(af[mi], bf[ni], acc[mi][ni], 0, 0, 0);
    }
  }

#pragma unroll
  for (int mi = 0; mi < 4; ++mi)
#pragma unroll
    for (int ni = 0; ni < 4; ++ni) {
      int gc = bn * 128 + wn * 64 + ni * 16 + lr;
      float bv = bias[gc];
#pragma unroll
      for (int r = 0; r < 4; ++r) {
        int gr = bm * 128 + wm * 64 + mi * 16 + lh * 4 + r;
        float v = acc[mi][ni][r] + bv;
        if (MODE == 0) {
          f16* x = (f16*)Cv;
          int b = gr >> 10, s = gr & 1023, h = gc >> 6, f = gc & 63;
          x[(size_t)((b * NH + h) * NS + s) * NF + f] = (f16)v;
        } else {
          ((float*)Cv)[(size_t)gr * DM + gc] = v;
        }
      }
    }
}

// ---------------------------------------------------------------------------
// transnorm: one pass over x per 64-row tile:
//   - xT[bh][f][s] = x[bh][s][f] (raw, for PV V-fragments)
//   - x <- x / ||x_row||  in place (Q/K operands)
// ---------------------------------------------------------------------------
__global__ __launch_bounds__(256) void transnorm_kernel(f16* __restrict__ x, f16* __restrict__ xT) {
  __shared__ f16 T[64][64];
  __shared__ float sinv[64];
  int bh = blockIdx.x >> 4, s0 = (blockIdx.x & 15) * 64;
  int tid = threadIdx.x;
  f16* xb = x + (size_t)bh * (NS * NF);
  half8 vv[2];
#pragma unroll
  for (int it = 0; it < 2; ++it) {
    int idx = it * 256 + tid;
    int sr = idx >> 3, fcb = idx & 7;
    half8 v = *(const half8*)(xb + (size_t)(s0 + sr) * NF + fcb * 8);
    vv[it] = v;
    *(half8*)&T[sr][((fcb ^ ((sr >> 3) & 7)) * 8)] = v;
    float s = 0.f;
#pragma unroll
    for (int j = 0; j < 8; ++j) {
      float u = (float)v[j];
      s += u * u;
    }
    s += __shfl_xor(s, 1, 64);
    s += __shfl_xor(s, 2, 64);
    s += __shfl_xor(s, 4, 64);
    if ((tid & 7) == 0) sinv[sr] = rsqrtf(s);
  }
  __syncthreads();
#pragma unroll
  for (int it = 0; it < 2; ++it) {
    int idx = it * 256 + tid;
    int fr = idx >> 3, scb = idx & 7;
    half8 v;
#pragma unroll
    for (int j = 0; j < 8; ++j) v[j] = T[scb * 8 + j][(((fr >> 3) ^ scb) * 8) + (fr & 7)];
    *(half8*)(xT + ((size_t)bh * NF + fr) * NS + s0 + scb * 8) = v;
  }
#pragma unroll
  for (int it = 0; it < 2; ++it) {
    int idx = it * 256 + tid;
    int sr = idx >> 3, fcb = idx & 7;
    float inv = sinv[sr];
    half8 v = vv[it], o;
#pragma unroll
    for (int j = 0; j < 8; ++j) o[j] = (f16)((float)v[j] * inv);
    *(half8*)(xb + (size_t)(s0 + sr) * NF + fcb * 8) = o;
  }
}

// ---------------------------------------------------------------------------
// attn v7: 1024 blocks (4 blocks/CU -> 4 waves/SIMD), 32 q per wave,
// KVBLK=64 double-buffered LDS staging (16 barrier pairs), pre-swizzled
// global_load_lds source, swapped QK^T, in-register softmax (fixed max=1),
// permlane32_swap P-redistribution, exp2-form exp.
// ---------------------------------------------------------------------------
__global__ __launch_bounds__(256, 4) void attn_kernel(const f16* __restrict__ xn, const f16* __restrict__ xT,
                                                      f16* __restrict__ ao) {
  __shared__ f16 KB[2][4096];  // [buf][64 t][64 f] rows 128B, col16 ^= (row&7)
  __shared__ f16 VB[2][4096];  // [buf][64 f][64 t] rows 128B, col16 ^= (row&7)

  int tid = threadIdx.x;
  int l = tid & 63, wv = tid >> 6;
  int lq = l & 31, hi = l >> 5;
  int kq = hi * 8;
  int xcd = blockIdx.x & 7, m = blockIdx.x >> 3;   // m in 0..127
  int bh = ((m >> 3) << 3) | xcd;                   // bh % 8 == xcd
  int q0 = (m & 7) * 128;
  const f16* xnb = xn + (size_t)bh * (NS * NF);
  const f16* xTb = xT + (size_t)bh * (NF * NS);

  // ---- staging source addresses (pre-swizzled; LDS dest linear) ----
  // rows covered per call: base + wv*8 + (l>>3); col16 = (l&7) ^ (l>>3)
  int srow = wv * 8 + (l >> 3);
  int scol = ((l & 7) ^ (l >> 3)) * 8;
  const f16* gK0 = xnb + (size_t)srow * NF + scol;       // + t0*NF (+32*NF for c1)
  const f16* gV0 = xTb + (size_t)srow * NS + scol;       // + t0    (+32*NS for c1)

  // Q fragments (B-operand of S^T): col = q, k = f
  half8 bq[4];
#pragma unroll
  for (int ks = 0; ks < 4; ++ks)
    bq[ks] = *(const half8*)(xnb + (size_t)(q0 + wv * 32 + lq) * NF + ks * 16 + kq);

  f32x16 accO[2];
  accO[0] = (f32x16)0.f;
  accO[1] = (f32x16)0.f;
  float rs = 0.f;

#define STAGE(buf, t0_)                                                                               \
  do {                                                                                                \
    __builtin_amdgcn_global_load_lds(                                                                 \
        (const __attribute__((address_space(1))) void*)(gK0 + (size_t)(t0_) * NF),                    \
        (__attribute__((address_space(3))) void*)(&KB[buf][wv * 512]), 16, 0, 0);                     \
    __builtin_amdgcn_global_load_lds(                                                                 \
        (const __attribute__((address_space(1))) void*)(gK0 + (size_t)(t0_ + 32) * NF),               \
        (__attribute__((address_space(3))) void*)(&KB[buf][2048 + wv * 512]), 16, 0, 0);              \
    __builtin_amdgcn_global_load_lds(                                                                 \
        (const __attribute__((address_space(1))) void*)(gV0 + (t0_)),                                 \
        (__attribute__((address_space(3))) void*)(&VB[buf][wv * 512]), 16, 0, 0);                     \
    __builtin_amdgcn_global_load_lds(                                                                 \
        (const __attribute__((address_space(1))) void*)(gV0 + (size_t)32 * NS + (t0_)),               \
        (__attribute__((address_space(3))) void*)(&VB[buf][2048 + wv * 512]), 16, 0, 0);              \
  } while (0)

  const float L2E = 1.4426950408889634f;

  STAGE(0, 0);
  asm volatile("s_waitcnt vmcnt(0)" ::: "memory");
  __syncthreads();

  int cur = 0;
  for (int t = 0; t < 16; ++t) {
    if (t < 15) STAGE(cur ^ 1, (t + 1) * 64);

    const char* kb = (const char*)&KB[cur][0];
    const char* vb = (const char*)&VB[cur][0];

#pragma unroll
    for (int ti = 0; ti < 2; ++ti) {
      // ---- K fragments for this 32-t subtile ----
      half8 ak[4];
#pragma unroll
      for (int ks = 0; ks < 4; ++ks)
        ak[ks] = *(const half8*)(kb + (ti * 32 + lq) * 128 + ((((ks * 2 + hi)) ^ (lq & 7)) << 4));

      // ---- S^T[t 32][q 32] ----
      f32x16 sa = (f32x16)0.f;
      __builtin_amdgcn_s_setprio(1);
#pragma unroll
      for (int ks = 0; ks < 4; ++ks)
        sa = __builtin_amdgcn_mfma_f32_32x32x16_f16(ak[ks], bq[ks], sa, 0, 0, 0);
      __builtin_amdgcn_s_setprio(0);

      // ---- p = exp(s-1) = exp2(s*log2e - log2e), quirk: s==0 -> 0 ----
      u32 pk[8];
#pragma unroll
      for (int mm = 0; mm < 8; ++mm) {
        float a = sa[2 * mm], b = sa[2 * mm + 1];
        float ea = (a == 0.f) ? 0.f : exp2f(__builtin_fmaf(a, L2E, -L2E));
        float eb = (b == 0.f) ? 0.f : exp2f(__builtin_fmaf(b, L2E, -L2E));
        rs += ea + eb;
        auto h = __builtin_amdgcn_cvt_pkrtz(ea, eb);
        pk[mm] = __builtin_bit_cast(u32, h);
      }
      // ---- redistribute P into PV A-fragments ----
      uint4 a0, a1;
#if __has_builtin(__builtin_amdgcn_permlane32_swap)
      {
        auto s02 = __builtin_amdgcn_permlane32_swap((int)pk[0], (int)pk[2], false, false);
        auto s13 = __builtin_amdgcn_permlane32_swap((int)pk[1], (int)pk[3], false, false);
        auto s46 = __builtin_amdgcn_permlane32_swap((int)pk[4], (int)pk[6], false, false);
        auto s57 = __builtin_amdgcn_permlane32_swap((int)pk[5], (int)pk[7], false, false);
        a0.x = (u32)s02[0]; a0.z = (u32)s02[1];
        a0.y = (u32)s13[0]; a0.w = (u32)s13[1];
        a1.x = (u32)s46[0]; a1.z = (u32)s46[1];
        a1.y = (u32)s57[0]; a1.w = (u32)s57[1];
      }
#else
      {
        u32 sw[8];
#pragma unroll
        for (int mm = 0; mm < 8; ++mm) sw[mm] = (u32)__shfl_xor((int)pk[mm], 32, 64);
        bool lo = (hi == 0);
        a0.x = lo ? pk[0] : sw[2];
        a0.y = lo ? pk[1] : sw[3];
        a0.z = lo ? sw[0] : pk[2];
        a0.w = lo ? sw[1] : pk[3];
        a1.x = lo ? pk[4] : sw[6];
        a1.y = lo ? pk[5] : sw[7];
        a1.z = lo ? sw[4] : pk[6];
        a1.w = lo ? sw[5] : pk[7];
      }
#endif
      half8 pa0 = __builtin_bit_cast(half8, a0);
      half8 pa1 = __builtin_bit_cast(half8, a1);
      // ---- PV: O[q][f] += P[q][t] * V[t][f] over this 32-t subtile ----
      __builtin_amdgcn_s_setprio(1);
#pragma unroll
      for (int sub = 0; sub < 2; ++sub) {
        half8 pa = sub ? pa1 : pa0;
#pragma unroll
        for (int ni = 0; ni < 2; ++ni) {
          half8 vbf = *(const half8*)(vb + (ni * 32 + lq) * 128 + (((ti * 4 + sub * 2 + hi) ^ (lq & 7)) << 4));
          accO[ni] = __builtin_amdgcn_mfma_f32_32x32x16_f16(pa, vbf, accO[ni], 0, 0, 0);
        }
      }
      __builtin_amdgcn_s_setprio(0);
    }

    asm volatile("s_waitcnt vmcnt(0)" ::: "memory");
    __syncthreads();
    cur ^= 1;
  }
#undef STAGE

  rs += __shfl_xor(rs, 32, 64);

  int b = bh >> 4, h = bh & 15;
#pragma unroll
  for (int r = 0; r < 16; ++r) {
    int qoff = (r & 3) + 8 * (r >> 2) + 4 * hi;
    float rv = __shfl(rs, qoff, 64);
    float rinv = 1.0f / rv;
    int qg = q0 + wv * 32 + qoff;
#pragma unroll
    for (int ni = 0; ni < 2; ++ni) {
      int f = ni * 32 + lq;
      ao[((size_t)(b * NS + qg)) * DM + h * NF + f] = (f16)(accO[ni][r] * rinv);
    }
  }
}

extern "C" void kernel_launch(void* const* d_in, const int* in_sizes, int n_in,
                              void* d_out, int out_size, void* d_ws, size_t ws_size,
                              hipStream_t stream) {
  const float* sin_in = (const float*)d_in[0];
  // d_in[1] = mask (presence-only in reference)
  const float* Wx = (const float*)d_in[2];
  const float* bx = (const float*)d_in[3];
  const float* Wp = (const float*)d_in[4];
  const float* bp = (const float*)d_in[5];
  float* out = (float*)d_out;

  char* p = (char*)d_ws;
  f16* sinb = (f16*)p;                      p += (size_t)NB * NS * DM * 2;      // also reused as ao
  f16* x    = (f16*)p;                      p += (size_t)NB * NH * NS * NF * 2; // normalized in place
  f16* xT   = (f16*)p;                      p += (size_t)NB * NH * NF * NS * 2;
  f16* W2T  = (f16*)p;                      p += (size_t)DM * DM * 2;
  f16* WpT  = (f16*)p;                      p += (size_t)DM * DM * 2;
  f16* ao   = sinb;  // sinb dead after gemm<0>

  csin_kernel<<<4096, 256, 0, stream>>>(sin_in, sinb);
  cwx_kernel<<<256, 256, 0, stream>>>(Wx, W2T);
  cwp_kernel<<<256, 256, 0, stream>>>(Wp, WpT);
  gemm_kernel<0><<<512, 256, 0, stream>>>(sinb, W2T, bx, (void*)x);
  transnorm_kernel<<<2048, 256, 0, stream>>>(x, xT);  // xT raw + x normalized
  attn_kernel<<<1024, 256, 0, stream>>>(x, xT, ao);
  gemm_kernel<1><<<512, 256, 0, stream>>>(ao, WpT, bp, (void*)out);
}

// Round 12
// 222.547 us; speedup vs baseline: 1.3451x; 1.0048x over previous
//
#include <hip/hip_runtime.h>
#include <hip/hip_bf16.h>
#include <math.h>

typedef _Float16 f16;
typedef _Float16 half8 __attribute__((ext_vector_type(8)));
typedef float f32x4 __attribute__((ext_vector_type(4)));
typedef float f32x16 __attribute__((ext_vector_type(16)));
typedef unsigned int u32;

#define NB 8
#define NS 1024
#define DM 1024
#define NH 16
#define NF 64

// ---------------------------------------------------------------------------
// cwx: W2T[h*64+f][d] = Wx[h][d][f] via LDS-tiled 64x64 transpose.
// ---------------------------------------------------------------------------
__global__ __launch_bounds__(256) void cwx_kernel(const float* __restrict__ Wx, f16* __restrict__ W2T) {
  __shared__ float T[64][65];
  int h = blockIdx.x >> 4, d0 = (blockIdx.x & 15) * 64;
  int tid = threadIdx.x;
  const float* src = Wx + ((size_t)h * 1024 + d0) * 64;
  int row = tid >> 2, cg = (tid & 3) * 16;
#pragma unroll
  for (int k = 0; k < 4; ++k) {
    float4 v = *(const float4*)(src + (size_t)row * 64 + cg + k * 4);
    T[row][cg + k * 4 + 0] = v.x;
    T[row][cg + k * 4 + 1] = v.y;
    T[row][cg + k * 4 + 2] = v.z;
    T[row][cg + k * 4 + 3] = v.w;
  }
  __syncthreads();
  int f = tid >> 2, dg = (tid & 3) * 16;
  f16 o[16];
#pragma unroll
  for (int j = 0; j < 16; ++j) o[j] = (f16)T[dg + j][f];
  *(half8*)(W2T + (size_t)(h * 64 + f) * DM + d0 + dg) = *(half8*)&o[0];
  *(half8*)(W2T + (size_t)(h * 64 + f) * DM + d0 + dg + 8) = *(half8*)&o[8];
}

// ---------------------------------------------------------------------------
// cwp: WpT[n][d] = Wp[d][n] via LDS-tiled 64x64 transpose.
// ---------------------------------------------------------------------------
__global__ __launch_bounds__(256) void cwp_kernel(const float* __restrict__ Wp, f16* __restrict__ WpT) {
  __shared__ float T[64][65];
  int n0 = (blockIdx.x >> 4) * 64, d0 = (blockIdx.x & 15) * 64;
  int tid = threadIdx.x;
  int row = tid >> 2, cg = (tid & 3) * 16;
#pragma unroll
  for (int k = 0; k < 4; ++k) {
    float4 v = *(const float4*)(Wp + (size_t)(d0 + row) * DM + n0 + cg + k * 4);
    T[row][cg + k * 4 + 0] = v.x;
    T[row][cg + k * 4 + 1] = v.y;
    T[row][cg + k * 4 + 2] = v.z;
    T[row][cg + k * 4 + 3] = v.w;
  }
  __syncthreads();
  int f = tid >> 2, dg = (tid & 3) * 16;
  f16 o[16];
#pragma unroll
  for (int j = 0; j < 16; ++j) o[j] = (f16)T[dg + j][f];
  *(half8*)(WpT + (size_t)(n0 + f) * DM + d0 + dg) = *(half8*)&o[0];
  *(half8*)(WpT + (size_t)(n0 + f) * DM + d0 + dg + 8) = *(half8*)&o[8];
}

// ---------------------------------------------------------------------------
// GEMM: C[8192,1024] = A @ Bt^T + bias. 128x128 tile, BK=64, XCD swizzle.
// MODE 0: A is f32 (sin) reg-staged with on-the-fly cvt; C -> f16 x[bhsf].
// MODE 1: A is f16 via global_load_lds; C -> f32 row-major out.
// ---------------------------------------------------------------------------
template <int MODE>
__global__ __launch_bounds__(256) void gemm_kernel(const void* __restrict__ Av, const f16* __restrict__ Bt,
                                                   const float* __restrict__ bias, void* __restrict__ Cv) {
  __shared__ f16 As[128][64];
  __shared__ f16 Bs[128][64];
  int tid = threadIdx.x;
  int l = tid & 63, wv = tid >> 6;
  int wm = wv >> 1, wn = wv & 1;
  int xcd = blockIdx.x & 7, m = blockIdx.x >> 3;
  int bm = ((m >> 3) << 3) | xcd;  // bm % 8 == xcd
  int bn = m & 7;
  int lr = l & 15, lh = l >> 4;

  f32x4 acc[4][4];
#pragma unroll
  for (int i = 0; i < 4; ++i)
#pragma unroll
    for (int j = 0; j < 4; ++j) acc[i][j] = (f32x4)0.f;

  int arow = bm * 128 + wv * 32 + (l >> 3), acol = (l & 7) * 8;
  const f16* gA = (const f16*)Av + (size_t)arow * DM + acol;      // MODE 1
  const float* gAf = (const float*)Av + (size_t)arow * DM + acol; // MODE 0
  const f16* gB = Bt + (size_t)(bn * 128 + wv * 32 + (l >> 3)) * DM + acol;
  f16* ldsA = &As[wv * 32][0];
  f16* ldsB = &Bs[wv * 32][0];

  for (int k0 = 0; k0 < DM; k0 += 64) {
    __syncthreads();
#pragma unroll
    for (int c = 0; c < 4; ++c) {
      if (MODE == 0) {
        const float* s = gAf + k0 + (size_t)c * 8 * DM;
        float4 u = *(const float4*)s, w = *(const float4*)(s + 4);
        uint4 hw;
        hw.x = __builtin_bit_cast(u32, __builtin_amdgcn_cvt_pkrtz(u.x, u.y));
        hw.y = __builtin_bit_cast(u32, __builtin_amdgcn_cvt_pkrtz(u.z, u.w));
        hw.z = __builtin_bit_cast(u32, __builtin_amdgcn_cvt_pkrtz(w.x, w.y));
        hw.w = __builtin_bit_cast(u32, __builtin_amdgcn_cvt_pkrtz(w.z, w.w));
        *(half8*)(ldsA + c * 512 + l * 8) = __builtin_bit_cast(half8, hw);
      } else {
        __builtin_amdgcn_global_load_lds(
            (const __attribute__((address_space(1))) void*)(gA + k0 + (size_t)c * 8 * DM),
            (__attribute__((address_space(3))) void*)(ldsA + c * 512), 16, 0, 0);
      }
      __builtin_amdgcn_global_load_lds(
          (const __attribute__((address_space(1))) void*)(gB + k0 + (size_t)c * 8 * DM),
          (__attribute__((address_space(3))) void*)(ldsB + c * 512), 16, 0, 0);
    }
    __syncthreads();
#pragma unroll
    for (int ks = 0; ks < 2; ++ks) {
      half8 af[4], bf[4];
#pragma unroll
      for (int mi = 0; mi < 4; ++mi) af[mi] = *(const half8*)&As[wm * 64 + mi * 16 + lr][ks * 32 + lh * 8];
#pragma unroll
      for (int ni = 0; ni < 4; ++ni) bf[ni] = *(const half8*)&Bs[wn * 64 + ni * 16 + lr][ks * 32 + lh * 8];
#pragma unroll
      for (int mi = 0; mi < 4; ++mi)
#pragma unroll
        for (int ni = 0; ni < 4; ++ni)
          acc[mi][ni] = __builtin_amdgcn_mfma_f32_16x16x32_f16(af[mi], bf[ni], acc[mi][ni], 0, 0, 0);
    }
  }

#pragma unroll
  for (int mi = 0; mi < 4; ++mi)
#pragma unroll
    for (int ni = 0; ni < 4; ++ni) {
      int gc = bn * 128 + wn * 64 + ni * 16 + lr;
      float bv = bias[gc];
#pragma unroll
      for (int r = 0; r < 4; ++r) {
        int gr = bm * 128 + wm * 64 + mi * 16 + lh * 4 + r;
        float v = acc[mi][ni][r] + bv;
        if (MODE == 0) {
          f16* x = (f16*)Cv;
          int b = gr >> 10, s = gr & 1023, h = gc >> 6, f = gc & 63;
          x[(size_t)((b * NH + h) * NS + s) * NF + f] = (f16)v;
        } else {
          ((float*)Cv)[(size_t)gr * DM + gc] = v;
        }
      }
    }
}

// ---------------------------------------------------------------------------
// transnorm: one pass over x per 64-row tile:
//   - xT[bh][f][s] = x[bh][s][f] (raw, for PV V-fragments)
//   - x <- x / ||x_row||  in place (Q/K operands)
// ---------------------------------------------------------------------------
__global__ __launch_bounds__(256) void transnorm_kernel(f16* __restrict__ x, f16* __restrict__ xT) {
  __shared__ f16 T[64][64];
  __shared__ float sinv[64];
  int bh = blockIdx.x >> 4, s0 = (blockIdx.x & 15) * 64;
  int tid = threadIdx.x;
  f16* xb = x + (size_t)bh * (NS * NF);
  half8 vv[2];
#pragma unroll
  for (int it = 0; it < 2; ++it) {
    int idx = it * 256 + tid;
    int sr = idx >> 3, fcb = idx & 7;
    half8 v = *(const half8*)(xb + (size_t)(s0 + sr) * NF + fcb * 8);
    vv[it] = v;
    *(half8*)&T[sr][((fcb ^ ((sr >> 3) & 7)) * 8)] = v;
    float s = 0.f;
#pragma unroll
    for (int j = 0; j < 8; ++j) {
      float u = (float)v[j];
      s += u * u;
    }
    s += __shfl_xor(s, 1, 64);
    s += __shfl_xor(s, 2, 64);
    s += __shfl_xor(s, 4, 64);
    if ((tid & 7) == 0) sinv[sr] = rsqrtf(s);
  }
  __syncthreads();
#pragma unroll
  for (int it = 0; it < 2; ++it) {
    int idx = it * 256 + tid;
    int fr = idx >> 3, scb = idx & 7;
    half8 v;
#pragma unroll
    for (int j = 0; j < 8; ++j) v[j] = T[scb * 8 + j][(((fr >> 3) ^ scb) * 8) + (fr & 7)];
    *(half8*)(xT + ((size_t)bh * NF + fr) * NS + s0 + scb * 8) = v;
  }
#pragma unroll
  for (int it = 0; it < 2; ++it) {
    int idx = it * 256 + tid;
    int sr = idx >> 3, fcb = idx & 7;
    float inv = sinv[sr];
    half8 v = vv[it], o;
#pragma unroll
    for (int j = 0; j < 8; ++j) o[j] = (f16)((float)v[j] * inv);
    *(half8*)(xb + (size_t)(s0 + sr) * NF + fcb * 8) = o;
  }
}

// ---------------------------------------------------------------------------
// attn v8: as v7 (4 blocks/CU, KVBLK=64 dbuf LDS staging, pre-swizzled
// global_load_lds, swapped QK^T, fixed-max softmax, permlane32_swap) PLUS
// rowsum via MFMA ones-trick: accR = mfma(pa, ones) -> rowsum lands in the
// same (r,hi) register layout as accO, killing the 16-deep serial VALU add
// chain and the entire epilogue shuffle reduction.
// ---------------------------------------------------------------------------
__global__ __launch_bounds__(256, 4) void attn_kernel(const f16* __restrict__ xn, const f16* __restrict__ xT,
                                                      f16* __restrict__ ao) {
  __shared__ f16 KB[2][4096];  // [buf][64 t][64 f] rows 128B, col16 ^= (row&7)
  __shared__ f16 VB[2][4096];  // [buf][64 f][64 t] rows 128B, col16 ^= (row&7)

  int tid = threadIdx.x;
  int l = tid & 63, wv = tid >> 6;
  int lq = l & 31, hi = l >> 5;
  int kq = hi * 8;
  int xcd = blockIdx.x & 7, m = blockIdx.x >> 3;   // m in 0..127
  int bh = ((m >> 3) << 3) | xcd;                   // bh % 8 == xcd
  int q0 = (m & 7) * 128;
  const f16* xnb = xn + (size_t)bh * (NS * NF);
  const f16* xTb = xT + (size_t)bh * (NF * NS);

  // ---- staging source addresses (pre-swizzled; LDS dest linear) ----
  int srow = wv * 8 + (l >> 3);
  int scol = ((l & 7) ^ (l >> 3)) * 8;
  const f16* gK0 = xnb + (size_t)srow * NF + scol;
  const f16* gV0 = xTb + (size_t)srow * NS + scol;

  // Q fragments (B-operand of S^T): col = q, k = f
  half8 bq[4];
#pragma unroll
  for (int ks = 0; ks < 4; ++ks)
    bq[ks] = *(const half8*)(xnb + (size_t)(q0 + wv * 32 + lq) * NF + ks * 16 + kq);

  half8 ones;
#pragma unroll
  for (int j = 0; j < 8; ++j) ones[j] = (f16)1.0f;

  f32x16 accO[2], accR;
  accO[0] = (f32x16)0.f;
  accO[1] = (f32x16)0.f;
  accR = (f32x16)0.f;

#define STAGE(buf, t0_)                                                                               \
  do {                                                                                                \
    __builtin_amdgcn_global_load_lds(                                                                 \
        (const __attribute__((address_space(1))) void*)(gK0 + (size_t)(t0_) * NF),                    \
        (__attribute__((address_space(3))) void*)(&KB[buf][wv * 512]), 16, 0, 0);                     \
    __builtin_amdgcn_global_load_lds(                                                                 \
        (const __attribute__((address_space(1))) void*)(gK0 + (size_t)(t0_ + 32) * NF),               \
        (__attribute__((address_space(3))) void*)(&KB[buf][2048 + wv * 512]), 16, 0, 0);              \
    __builtin_amdgcn_global_load_lds(                                                                 \
        (const __attribute__((address_space(1))) void*)(gV0 + (t0_)),                                 \
        (__attribute__((address_space(3))) void*)(&VB[buf][wv * 512]), 16, 0, 0);                     \
    __builtin_amdgcn_global_load_lds(                                                                 \
        (const __attribute__((address_space(1))) void*)(gV0 + (size_t)32 * NS + (t0_)),               \
        (__attribute__((address_space(3))) void*)(&VB[buf][2048 + wv * 512]), 16, 0, 0);              \
  } while (0)

  const float L2E = 1.4426950408889634f;

  STAGE(0, 0);
  asm volatile("s_waitcnt vmcnt(0)" ::: "memory");
  __syncthreads();

  int cur = 0;
  for (int t = 0; t < 16; ++t) {
    if (t < 15) STAGE(cur ^ 1, (t + 1) * 64);

    const char* kb = (const char*)&KB[cur][0];
    const char* vb = (const char*)&VB[cur][0];

#pragma unroll
    for (int ti = 0; ti < 2; ++ti) {
      // ---- K fragments for this 32-t subtile ----
      half8 ak[4];
#pragma unroll
      for (int ks = 0; ks < 4; ++ks)
        ak[ks] = *(const half8*)(kb + (ti * 32 + lq) * 128 + ((((ks * 2 + hi)) ^ (lq & 7)) << 4));

      // ---- S^T[t 32][q 32] ----
      f32x16 sa = (f32x16)0.f;
      __builtin_amdgcn_s_setprio(1);
#pragma unroll
      for (int ks = 0; ks < 4; ++ks)
        sa = __builtin_amdgcn_mfma_f32_32x32x16_f16(ak[ks], bq[ks], sa, 0, 0, 0);
      __builtin_amdgcn_s_setprio(0);

      // ---- p = exp(s-1) = exp2(s*log2e - log2e), quirk: s==0 -> 0 ----
      u32 pk[8];
#pragma unroll
      for (int mm = 0; mm < 8; ++mm) {
        float a = sa[2 * mm], b = sa[2 * mm + 1];
        float ea = (a == 0.f) ? 0.f : exp2f(__builtin_fmaf(a, L2E, -L2E));
        float eb = (b == 0.f) ? 0.f : exp2f(__builtin_fmaf(b, L2E, -L2E));
        auto h = __builtin_amdgcn_cvt_pkrtz(ea, eb);
        pk[mm] = __builtin_bit_cast(u32, h);
      }
      // ---- redistribute P into PV A-fragments ----
      uint4 a0, a1;
#if __has_builtin(__builtin_amdgcn_permlane32_swap)
      {
        auto s02 = __builtin_amdgcn_permlane32_swap((int)pk[0], (int)pk[2], false, false);
        auto s13 = __builtin_amdgcn_permlane32_swap((int)pk[1], (int)pk[3], false, false);
        auto s46 = __builtin_amdgcn_permlane32_swap((int)pk[4], (int)pk[6], false, false);
        auto s57 = __builtin_amdgcn_permlane32_swap((int)pk[5], (int)pk[7], false, false);
        a0.x = (u32)s02[0]; a0.z = (u32)s02[1];
        a0.y = (u32)s13[0]; a0.w = (u32)s13[1];
        a1.x = (u32)s46[0]; a1.z = (u32)s46[1];
        a1.y = (u32)s57[0]; a1.w = (u32)s57[1];
      }
#else
      {
        u32 sw[8];
#pragma unroll
        for (int mm = 0; mm < 8; ++mm) sw[mm] = (u32)__shfl_xor((int)pk[mm], 32, 64);
        bool lo = (hi == 0);
        a0.x = lo ? pk[0] : sw[2];
        a0.y = lo ? pk[1] : sw[3];
        a0.z = lo ? sw[0] : pk[2];
        a0.w = lo ? sw[1] : pk[3];
        a1.x = lo ? pk[4] : sw[6];
        a1.y = lo ? pk[5] : sw[7];
        a1.z = lo ? sw[4] : pk[6];
        a1.w = lo ? sw[5] : pk[7];
      }
#endif
      half8 pa0 = __builtin_bit_cast(half8, a0);
      half8 pa1 = __builtin_bit_cast(half8, a1);
      // ---- PV + MFMA rowsum over this 32-t subtile ----
      __builtin_amdgcn_s_setprio(1);
      accR = __builtin_amdgcn_mfma_f32_32x32x16_f16(pa0, ones, accR, 0, 0, 0);
      accR = __builtin_amdgcn_mfma_f32_32x32x16_f16(pa1, ones, accR, 0, 0, 0);
#pragma unroll
      for (int sub = 0; sub < 2; ++sub) {
        half8 pa = sub ? pa1 : pa0;
#pragma unroll
        for (int ni = 0; ni < 2; ++ni) {
          half8 vbf = *(const half8*)(vb + (ni * 32 + lq) * 128 + (((ti * 4 + sub * 2 + hi) ^ (lq & 7)) << 4));
          accO[ni] = __builtin_amdgcn_mfma_f32_32x32x16_f16(pa, vbf, accO[ni], 0, 0, 0);
        }
      }
      __builtin_amdgcn_s_setprio(0);
    }

    asm volatile("s_waitcnt vmcnt(0)" ::: "memory");
    __syncthreads();
    cur ^= 1;
  }
#undef STAGE

  int b = bh >> 4, h = bh & 15;
#pragma unroll
  for (int r = 0; r < 16; ++r) {
    int qoff = (r & 3) + 8 * (r >> 2) + 4 * hi;
    float rinv = 1.0f / accR[r];   // rowsum for q-row qoff, lane-local
    int qg = q0 + wv * 32 + qoff;
#pragma unroll
    for (int ni = 0; ni < 2; ++ni) {
      int f = ni * 32 + lq;
      ao[((size_t)(b * NS + qg)) * DM + h * NF + f] = (f16)(accO[ni][r] * rinv);
    }
  }
}

extern "C" void kernel_launch(void* const* d_in, const int* in_sizes, int n_in,
                              void* d_out, int out_size, void* d_ws, size_t ws_size,
                              hipStream_t stream) {
  const float* sin_in = (const float*)d_in[0];
  // d_in[1] = mask (presence-only in reference)
  const float* Wx = (const float*)d_in[2];
  const float* bx = (const float*)d_in[3];
  const float* Wp = (const float*)d_in[4];
  const float* bp = (const float*)d_in[5];
  float* out = (float*)d_out;

  char* p = (char*)d_ws;
  f16* ao   = (f16*)p;                      p += (size_t)NB * NS * DM * 2;
  f16* x    = (f16*)p;                      p += (size_t)NB * NH * NS * NF * 2; // normalized in place
  f16* xT   = (f16*)p;                      p += (size_t)NB * NH * NF * NS * 2;
  f16* W2T  = (f16*)p;                      p += (size_t)DM * DM * 2;
  f16* WpT  = (f16*)p;                      p += (size_t)DM * DM * 2;

  cwx_kernel<<<256, 256, 0, stream>>>(Wx, W2T);
  cwp_kernel<<<256, 256, 0, stream>>>(Wp, WpT);
  gemm_kernel<0><<<512, 256, 0, stream>>>((const void*)sin_in, W2T, bx, (void*)x);  // f32 A, fused cast
  transnorm_kernel<<<2048, 256, 0, stream>>>(x, xT);  // xT raw + x normalized
  attn_kernel<<<1024, 256, 0, stream>>>(x, xT, ao);
  gemm_kernel<1><<<512, 256, 0, stream>>>((const void*)ao, WpT, bp, (void*)out);
}